// Round 3
// baseline (612.328 us; speedup 1.0000x reference)
//
#include <hip/hip_runtime.h>
#include <stdint.h>

#define N 384
#define NR (N*N)        // 147456
#define C 128

typedef unsigned short ushort_t;
typedef __attribute__((ext_vector_type(8))) short bf16x8;
typedef __attribute__((ext_vector_type(4))) float f32x4;

__device__ __forceinline__ float bf2f(ushort_t u) {
  union { unsigned int i; float f; } v; v.i = ((unsigned int)u) << 16; return v.f;
}
__device__ __forceinline__ ushort_t f2bf(float f) {
  union { float f; unsigned int i; } v; v.f = f;
  unsigned int u = v.i + 0x7FFF + ((v.i >> 16) & 1);
  return (ushort_t)(u >> 16);
}
__device__ __forceinline__ float sigmoidf_(float x) {
  return 1.0f / (1.0f + __expf(-x));
}
__device__ __forceinline__ void unpack8(uint4 q, float f[8]) {
  const unsigned int* w = (const unsigned int*)&q;
#pragma unroll
  for (int e = 0; e < 4; ++e) {
    f[2*e]   = bf2f((ushort_t)(w[e] & 0xffffu));
    f[2*e+1] = bf2f((ushort_t)(w[e] >> 16));
  }
}
__device__ __forceinline__ uint4 pack8(const float f[8]) {
  uint4 q;
  unsigned int* w = (unsigned int*)&q;
#pragma unroll
  for (int e = 0; e < 4; ++e)
    w[e] = (unsigned int)f2bf(f[2*e]) | ((unsigned int)f2bf(f[2*e+1]) << 16);
  return q;
}

// ---- dtype-dual IO helpers (isf32 is wave-uniform) ---------------------
__device__ __forceinline__ void load8f(const void* p, size_t idx, int isf32, float f[8]) {
  if (isf32) {
    const float* q = (const float*)p + idx;
    const float4 a = ((const float4*)q)[0];
    const float4 b = ((const float4*)q)[1];
    f[0]=a.x; f[1]=a.y; f[2]=a.z; f[3]=a.w;
    f[4]=b.x; f[5]=b.y; f[6]=b.z; f[7]=b.w;
  } else {
    unpack8(*(const uint4*)((const ushort_t*)p + idx), f);
  }
}
__device__ __forceinline__ bf16x8 load8frag(const void* p, size_t idx, int isf32) {
  if (isf32) {
    float f[8]; load8f(p, idx, 1, f);
    union { alignas(16) ushort_t w[8]; bf16x8 v; } u;
#pragma unroll
    for (int e = 0; e < 8; ++e) u.w[e] = f2bf(f[e]);
    return u.v;
  }
  return *(const bf16x8*)((const ushort_t*)p + idx);
}
__device__ __forceinline__ void store8(void* p, size_t idx, int isf32, const float f[8]) {
  if (isf32) {
    float* q = (float*)p + idx;
    ((float4*)q)[0] = make_float4(f[0], f[1], f[2], f[3]);
    ((float4*)q)[1] = make_float4(f[4], f[5], f[6], f[7]);
  } else {
    *(uint4*)((ushort_t*)p + idx) = pack8(f);
  }
}
__device__ __forceinline__ void store1(void* p, size_t idx, int isf32, float v) {
  if (isf32) ((float*)p)[idx] = v;
  else       ((ushort_t*)p)[idx] = f2bf(v);
}

// ---- dtype detector: fp32 N(0,1) words have exponent in [87,132] -------
__global__ void kdetect(const unsigned int* __restrict__ z, int* __restrict__ flag) {
  const int t = threadIdx.x;
  __shared__ int cnt[4];
  unsigned int u = z[t];
  int e = (u >> 23) & 0xFF;
  int sane = (e >= 87 && e <= 132) ? 1 : 0;
  unsigned long long b = __ballot(sane);
  if ((t & 63) == 0) cnt[t >> 6] = __popcll(b);
  __syncthreads();
  if (t == 0) flag[0] = ((cnt[0] + cnt[1] + cnt[2] + cnt[3]) >= 128) ? 1 : 0;
}

// ---------------- K1: fused LN(z) + 5 projections -----------------------
// zs: 128x128 bf16 tile, XOR-swizzled 16B chunks: phys_chunk = g_chunk ^ (row&7)
// tb: 64x136 bf16 transpose buffer (half of the 128 channels at a time)

__device__ __forceinline__ void do_pair(const ushort_t* zs, ushort_t* tb,
    const void* __restrict__ W1, const void* __restrict__ W2,
    ushort_t* __restrict__ dst, int R0, int isf32)
{
  const int t = threadIdx.x;
  const int wave = t >> 6, lane = t & 63;
  const int quad = lane >> 4, l16 = lane & 15;
  f32x4 acc1[2][8], acc2[2][8];
  const f32x4 z4 = {0.f, 0.f, 0.f, 0.f};
#pragma unroll
  for (int mf = 0; mf < 2; ++mf)
#pragma unroll
    for (int nf = 0; nf < 8; ++nf) { acc1[mf][nf] = z4; acc2[mf][nf] = z4; }

#pragma unroll
  for (int ks = 0; ks < 4; ++ks) {
    bf16x8 af[2];
#pragma unroll
    for (int mf = 0; mf < 2; ++mf) {
      int row = wave*32 + mf*16 + l16;
      int ph = (ks*4 + quad) ^ (row & 7);
      af[mf] = *(const bf16x8*)(zs + row*128 + ph*8);
    }
#pragma unroll
    for (int nf = 0; nf < 8; ++nf) {
      int cidx = nf*16 + l16;
      bf16x8 b1 = load8frag(W1, (size_t)cidx*128 + ks*32 + quad*8, isf32);
      bf16x8 b2 = load8frag(W2, (size_t)cidx*128 + ks*32 + quad*8, isf32);
#pragma unroll
      for (int mf = 0; mf < 2; ++mf) {
        acc1[mf][nf] = __builtin_amdgcn_mfma_f32_16x16x32_bf16(af[mf], b1, acc1[mf][nf], 0, 0, 0);
        acc2[mf][nf] = __builtin_amdgcn_mfma_f32_16x16x32_bf16(af[mf], b2, acc2[mf][nf], 0, 0, 0);
      }
    }
  }
  // epilogue: gate, transpose through LDS in two 64-channel halves, store [d][R]
#pragma unroll
  for (int half = 0; half < 2; ++half) {
#pragma unroll
    for (int mf = 0; mf < 2; ++mf)
#pragma unroll
      for (int nf4 = 0; nf4 < 4; ++nf4) {
        int nf = half*4 + nf4;
#pragma unroll
        for (int r = 0; r < 4; ++r) {
          int row = wave*32 + mf*16 + quad*4 + r;
          int col = nf4*16 + l16;
          float v = acc2[mf][nf][r] * sigmoidf_(acc1[mf][nf][r]);
          tb[col*136 + row] = f2bf(v);
        }
      }
    __syncthreads();
#pragma unroll
    for (int i = 0; i < 4; ++i) {
      int cid = t + i*256;           // 64 d x 16 row-chunks
      int dl = cid >> 4, rc = cid & 15;
      uint4 v = *(const uint4*)(tb + dl*136 + rc*8);
      *(uint4*)(dst + (size_t)(half*64 + dl)*NR + R0 + rc*8) = v;
    }
    __syncthreads();
  }
}

__device__ __forceinline__ void do_single(const ushort_t* zs,
    const void* __restrict__ W, void* __restrict__ gout, int R0, int isf32)
{
  const int t = threadIdx.x;
  const int wave = t >> 6, lane = t & 63;
  const int quad = lane >> 4, l16 = lane & 15;
  f32x4 acc[2][8];
  const f32x4 z4 = {0.f, 0.f, 0.f, 0.f};
#pragma unroll
  for (int mf = 0; mf < 2; ++mf)
#pragma unroll
    for (int nf = 0; nf < 8; ++nf) acc[mf][nf] = z4;
#pragma unroll
  for (int ks = 0; ks < 4; ++ks) {
    bf16x8 af[2];
#pragma unroll
    for (int mf = 0; mf < 2; ++mf) {
      int row = wave*32 + mf*16 + l16;
      int ph = (ks*4 + quad) ^ (row & 7);
      af[mf] = *(const bf16x8*)(zs + row*128 + ph*8);
    }
#pragma unroll
    for (int nf = 0; nf < 8; ++nf) {
      int cidx = nf*16 + l16;
      bf16x8 b = load8frag(W, (size_t)cidx*128 + ks*32 + quad*8, isf32);
#pragma unroll
      for (int mf = 0; mf < 2; ++mf)
        acc[mf][nf] = __builtin_amdgcn_mfma_f32_16x16x32_bf16(af[mf], b, acc[mf][nf], 0, 0, 0);
    }
  }
#pragma unroll
  for (int mf = 0; mf < 2; ++mf)
#pragma unroll
    for (int nf = 0; nf < 8; ++nf)
#pragma unroll
      for (int r = 0; r < 4; ++r) {
        int row = wave*32 + mf*16 + quad*4 + r;
        int col = nf*16 + l16;
        store1(gout, (size_t)(R0 + row)*C + col, isf32, sigmoidf_(acc[mf][nf][r]));
      }
}

__global__ __launch_bounds__(256, 2)
void k1(const void* __restrict__ z, const void* __restrict__ gin,
        const void* __restrict__ bin,
        const void* __restrict__ Wa1, const void* __restrict__ Wa2,
        const void* __restrict__ Wb1, const void* __restrict__ Wb2,
        const void* __restrict__ Wg,
        ushort_t* __restrict__ a_t, ushort_t* __restrict__ b_t,
        void* __restrict__ gout, const int* __restrict__ flag)
{
  __shared__ ushort_t zs[128*128];
  __shared__ ushort_t tb[64*136];
  const int t = threadIdx.x;
  const int isf32 = *flag;
  const int R0 = blockIdx.x * 128;

  // zero-init LDS (paranoia: no junk can survive)
  {
    const uint4 zz = {0u, 0u, 0u, 0u};
    uint4* zp = (uint4*)zs;
    for (int i = t; i < 2048; i += 256) zp[i] = zz;
    uint4* tp = (uint4*)tb;
    for (int i = t; i < 1088; i += 256) tp[i] = zz;
  }
  __syncthreads();

  // stage z (swizzled, converted to bf16)
#pragma unroll
  for (int i = 0; i < 8; ++i) {
    int cid = t + i*256;
    int row = cid >> 4, p = cid & 15;
    int gch = p ^ (row & 7);
    float f[8];
    load8f(z, (size_t)(R0 + row)*C + gch*8, isf32, f);
    *(uint4*)(zs + row*128 + p*8) = pack8(f);
  }
  __syncthreads();

  // layernorm rows in-place (2 threads per row)
  {
    const int r = t >> 1, h = t & 1;
    uint4 q[8];
    float sum = 0.f, sq = 0.f;
#pragma unroll
    for (int j = 0; j < 8; ++j) {
      const int ph = (h*8 + j) ^ (r & 7);
      q[j] = *(const uint4*)(zs + r*128 + ph*8);
      float f[8]; unpack8(q[j], f);
#pragma unroll
      for (int e = 0; e < 8; ++e) { sum += f[e]; sq += f[e]*f[e]; }
    }
    sum += __shfl_xor(sum, 1);
    sq  += __shfl_xor(sq, 1);
    const float mu = sum * 0.0078125f;
    const float rstd = rsqrtf(sq * 0.0078125f - mu*mu + 1e-5f);
#pragma unroll
    for (int j = 0; j < 8; ++j) {
      const int g = h*8 + j;
      const int ph = g ^ (r & 7);
      float f[8], gm[8], bt[8];
      unpack8(q[j], f);
      load8f(gin, (size_t)g*8, isf32, gm);
      load8f(bin, (size_t)g*8, isf32, bt);
#pragma unroll
      for (int e = 0; e < 8; ++e) f[e] = (f[e] - mu) * rstd * gm[e] + bt[e];
      *(uint4*)(zs + r*128 + ph*8) = pack8(f);
    }
  }
  __syncthreads();

  do_pair(zs, tb, Wa1, Wa2, a_t, R0, isf32);
  do_pair(zs, tb, Wb1, Wb2, b_t, R0, isf32);
  do_single(zs, Wg, gout, R0, isf32);
}

// ---------------- K2: s_d = A_d * B_d^T per channel ---------------------
__global__ __launch_bounds__(256, 2)
void k2(const ushort_t* __restrict__ a_t, const ushort_t* __restrict__ b_t,
        ushort_t* __restrict__ s_t)
{
  __shared__ ushort_t As[128*64];
  __shared__ ushort_t Bs[128*64];
  const int t = threadIdx.x;
  const int wave = t >> 6, lane = t & 63;
  const int quad = lane >> 4, l16 = lane & 15;
  const int wm = wave >> 1, wn = wave & 1;
  const int d = blockIdx.y;
  const int i0 = (blockIdx.x / 3) * 128, j0 = (blockIdx.x % 3) * 128;
  const size_t dbase = (size_t)d * NR;

  {
    const uint4 zz = {0u, 0u, 0u, 0u};
    uint4* ap = (uint4*)As;
    uint4* bp = (uint4*)Bs;
    for (int i = t; i < 1024; i += 256) { ap[i] = zz; bp[i] = zz; }
  }

  f32x4 acc[4][4];
  const f32x4 z4 = {0.f, 0.f, 0.f, 0.f};
#pragma unroll
  for (int mf = 0; mf < 4; ++mf)
#pragma unroll
    for (int nf = 0; nf < 4; ++nf) acc[mf][nf] = z4;

  for (int kt = 0; kt < 6; ++kt) {
    uint4 va[4], vb[4];
#pragma unroll
    for (int j = 0; j < 4; ++j) {
      int cid = t + j*256;                 // 1024 chunk-slots: 128 rows x 8 chunks
      int row = cid >> 3, c = cid & 7;
      va[j] = *(const uint4*)(a_t + dbase + (size_t)(i0 + row)*N + kt*64 + c*8);
      vb[j] = *(const uint4*)(b_t + dbase + (size_t)(j0 + row)*N + kt*64 + c*8);
    }
    __syncthreads();                       // previous iteration's reads complete
#pragma unroll
    for (int j = 0; j < 4; ++j) {
      int cid = t + j*256;
      int row = cid >> 3, c = cid & 7;
      int p = c ^ (row & 7);               // swizzle: conflict-free frag reads
      *(uint4*)(As + row*64 + p*8) = va[j];
      *(uint4*)(Bs + row*64 + p*8) = vb[j];
    }
    __syncthreads();                       // writes visible to all waves

#pragma unroll
    for (int ks = 0; ks < 2; ++ks) {
      bf16x8 af[4], bfr[4];
#pragma unroll
      for (int f = 0; f < 4; ++f) {
        int ra = wm*64 + f*16 + l16;
        int pa = (ks*4 + quad) ^ (ra & 7);
        af[f] = *(const bf16x8*)(As + ra*64 + pa*8);
        int rb = wn*64 + f*16 + l16;
        int pb = (ks*4 + quad) ^ (rb & 7);
        bfr[f] = *(const bf16x8*)(Bs + rb*64 + pb*8);
      }
#pragma unroll
      for (int mf = 0; mf < 4; ++mf)
#pragma unroll
        for (int nf = 0; nf < 4; ++nf)
          acc[mf][nf] = __builtin_amdgcn_mfma_f32_16x16x32_bf16(af[mf], bfr[nf], acc[mf][nf], 0, 0, 0);
    }
  }
#pragma unroll
  for (int mf = 0; mf < 4; ++mf)
#pragma unroll
    for (int nf = 0; nf < 4; ++nf)
#pragma unroll
      for (int r = 0; r < 4; ++r) {
        int row = wm*64 + mf*16 + quad*4 + r;
        int col = wn*64 + nf*16 + l16;
        s_t[dbase + (size_t)(i0 + row)*N + j0 + col] = f2bf(acc[mf][nf][r]);
      }
}

// ---------------- K3: out = g * (LN(s) @ Wout^T) ------------------------
__global__ __launch_bounds__(256, 3)
void k3(const ushort_t* __restrict__ s_t, const void* __restrict__ gno,
        const void* __restrict__ bno, const void* __restrict__ Wout,
        void* __restrict__ io, const int* __restrict__ flag)
{
  __shared__ ushort_t ss[128*136];
  const int t = threadIdx.x;
  const int isf32 = *flag;
  const int wave = t >> 6, lane = t & 63;
  const int quad = lane >> 4, l16 = lane & 15;
  const int R0 = blockIdx.x * 128;

  {
    const uint4 zz = {0u, 0u, 0u, 0u};
    uint4* sp = (uint4*)ss;
    for (int i = t; i < 2176; i += 256) sp[i] = zz;
  }
  __syncthreads();

  // stage s tile [d][R] -> LDS [R][d] via 8x8 register transpose
  {
    const int dg = t >> 4, rg = t & 15;
    const int d0 = dg * 8;
    uint4 v[8];
#pragma unroll
    for (int dd = 0; dd < 8; ++dd)
      v[dd] = *(const uint4*)(s_t + (size_t)(d0 + dd)*NR + R0 + rg*8);
    const ushort_t* sv = (const ushort_t*)v;
#pragma unroll
    for (int rr0 = 0; rr0 < 8; ++rr0) {
      int rr = (rr0 + (t & 7)) & 7;          // lane stagger: kills bank conflicts
      ushort_t w[8];
#pragma unroll
      for (int dd = 0; dd < 8; ++dd) w[dd] = sv[dd*8 + rr];
      *(uint4*)(ss + (rg*8 + rr)*136 + d0) = *(const uint4*)w;
    }
  }
  __syncthreads();

  // layernorm over d (2 threads per row)
  {
    const int r = t >> 1, h = t & 1;
    uint4 q[8];
    float sum = 0.f, sq = 0.f;
#pragma unroll
    for (int j = 0; j < 8; ++j) {
      q[j] = *(const uint4*)(ss + r*136 + (h*8 + j)*8);
      float f[8]; unpack8(q[j], f);
#pragma unroll
      for (int e = 0; e < 8; ++e) { sum += f[e]; sq += f[e]*f[e]; }
    }
    sum += __shfl_xor(sum, 1);
    sq  += __shfl_xor(sq, 1);
    const float mu = sum * 0.0078125f;
    const float rstd = rsqrtf(sq * 0.0078125f - mu*mu + 1e-5f);
#pragma unroll
    for (int j = 0; j < 8; ++j) {
      const int g = h*8 + j;
      float f[8], gm[8], bt[8];
      unpack8(q[j], f);
      load8f(gno, (size_t)g*8, isf32, gm);
      load8f(bno, (size_t)g*8, isf32, bt);
#pragma unroll
      for (int e = 0; e < 8; ++e) f[e] = (f[e] - mu) * rstd * gm[e] + bt[e];
      *(uint4*)(ss + r*136 + g*8) = pack8(f);
    }
  }
  __syncthreads();   // LN writes visible before GEMM fragment reads

  f32x4 acc[2][8];
  const f32x4 z4 = {0.f, 0.f, 0.f, 0.f};
#pragma unroll
  for (int mf = 0; mf < 2; ++mf)
#pragma unroll
    for (int nf = 0; nf < 8; ++nf) acc[mf][nf] = z4;
#pragma unroll
  for (int ks = 0; ks < 4; ++ks) {
    bf16x8 af[2];
#pragma unroll
    for (int mf = 0; mf < 2; ++mf) {
      int row = wave*32 + mf*16 + l16;
      af[mf] = *(const bf16x8*)(ss + row*136 + (ks*4 + quad)*8);
    }
#pragma unroll
    for (int nf = 0; nf < 8; ++nf) {
      int cidx = nf*16 + l16;
      bf16x8 b = load8frag(Wout, (size_t)cidx*128 + ks*32 + quad*8, isf32);
#pragma unroll
      for (int mf = 0; mf < 2; ++mf)
        acc[mf][nf] = __builtin_amdgcn_mfma_f32_16x16x32_bf16(af[mf], b, acc[mf][nf], 0, 0, 0);
    }
  }
  __syncthreads();   // all fragment reads complete before h write-back

#pragma unroll
  for (int mf = 0; mf < 2; ++mf)
#pragma unroll
    for (int nf = 0; nf < 8; ++nf)
#pragma unroll
      for (int r = 0; r < 4; ++r) {
        int row = wave*32 + mf*16 + quad*4 + r;
        int col = nf*16 + l16;
        ss[row*136 + col] = f2bf(acc[mf][nf][r]);
      }
  __syncthreads();

  // gated store: out = g * h, fully vectorized
#pragma unroll
  for (int i = 0; i < 8; ++i) {
    int cid = t + i*256;
    int row = cid >> 4, ch = cid & 15;
    float gf[8], hf[8], of[8];
    load8f(io, (size_t)(R0 + row)*C + ch*8, isf32, gf);
    unpack8(*(const uint4*)(ss + row*136 + ch*8), hf);
#pragma unroll
    for (int e = 0; e < 8; ++e) of[e] = gf[e] * hf[e];
    store8(io, (size_t)(R0 + row)*C + ch*8, isf32, of);
  }
}

extern "C" void kernel_launch(void* const* d_in, const int* in_sizes, int n_in,
                              void* d_out, int out_size, void* d_ws, size_t ws_size,
                              hipStream_t stream) {
  (void)in_sizes; (void)n_in; (void)out_size; (void)ws_size;
  const void* z    = d_in[0];
  const void* gin  = d_in[1];
  const void* bin  = d_in[2];
  const void* gno  = d_in[3];
  const void* bno  = d_in[4];
  const void* Wa1  = d_in[5];
  const void* Wa2  = d_in[6];
  const void* Wb1  = d_in[7];
  const void* Wb2  = d_in[8];
  const void* Wg   = d_in[9];
  const void* Wout = d_in[10];

  int* flag = (int*)d_ws;                                     // 256 B reserved
  ushort_t* a_t = (ushort_t*)((char*)d_ws + 256);             // [128][147456] bf16
  ushort_t* b_t = a_t + (size_t)NR * C;
  ushort_t* s_t = b_t + (size_t)NR * C;

  kdetect<<<1, 256, 0, stream>>>((const unsigned int*)z, flag);
  k1<<<NR/128, 256, 0, stream>>>(z, gin, bin, Wa1, Wa2, Wb1, Wb2, Wg, a_t, b_t, d_out, flag);
  k2<<<dim3(9, 128), 256, 0, stream>>>(a_t, b_t, s_t);
  k3<<<NR/128, 256, 0, stream>>>(s_t, gno, bno, Wout, d_out, flag);
}

// Round 4
// 461.206 us; speedup vs baseline: 1.3277x; 1.3277x over previous
//
#include <hip/hip_runtime.h>
#include <stdint.h>

#define N 384
#define NR (N*N)        // 147456
#define C 128
#define WSZ 16384       // 128x128 elements per weight

typedef unsigned short ushort_t;
typedef __attribute__((ext_vector_type(8))) short bf16x8;
typedef __attribute__((ext_vector_type(4))) float f32x4;

__device__ __forceinline__ float bf2f(ushort_t u) {
  union { unsigned int i; float f; } v; v.i = ((unsigned int)u) << 16; return v.f;
}
__device__ __forceinline__ ushort_t f2bf(float f) {
  union { float f; unsigned int i; } v; v.f = f;
  unsigned int u = v.i + 0x7FFF + ((v.i >> 16) & 1);
  return (ushort_t)(u >> 16);
}
__device__ __forceinline__ float sigmoidf_(float x) {
  return 1.0f / (1.0f + __expf(-x));
}
__device__ __forceinline__ void unpack8(uint4 q, float f[8]) {
  const unsigned int* w = (const unsigned int*)&q;
#pragma unroll
  for (int e = 0; e < 4; ++e) {
    f[2*e]   = bf2f((ushort_t)(w[e] & 0xffffu));
    f[2*e+1] = bf2f((ushort_t)(w[e] >> 16));
  }
}
__device__ __forceinline__ uint4 pack8(const float f[8]) {
  uint4 q;
  unsigned int* w = (unsigned int*)&q;
#pragma unroll
  for (int e = 0; e < 4; ++e)
    w[e] = (unsigned int)f2bf(f[2*e]) | ((unsigned int)f2bf(f[2*e+1]) << 16);
  return q;
}

// ---- dtype-dual IO helpers (isf32 is wave-uniform) ---------------------
__device__ __forceinline__ void load8f(const void* p, size_t idx, int isf32, float f[8]) {
  if (isf32) {
    const float* q = (const float*)p + idx;
    const float4 a = ((const float4*)q)[0];
    const float4 b = ((const float4*)q)[1];
    f[0]=a.x; f[1]=a.y; f[2]=a.z; f[3]=a.w;
    f[4]=b.x; f[5]=b.y; f[6]=b.z; f[7]=b.w;
  } else {
    unpack8(*(const uint4*)((const ushort_t*)p + idx), f);
  }
}
__device__ __forceinline__ void store8(void* p, size_t idx, int isf32, const float f[8]) {
  if (isf32) {
    float* q = (float*)p + idx;
    ((float4*)q)[0] = make_float4(f[0], f[1], f[2], f[3]);
    ((float4*)q)[1] = make_float4(f[4], f[5], f[6], f[7]);
  } else {
    *(uint4*)((ushort_t*)p + idx) = pack8(f);
  }
}
__device__ __forceinline__ void store1(void* p, size_t idx, int isf32, float v) {
  if (isf32) ((float*)p)[idx] = v;
  else       ((ushort_t*)p)[idx] = f2bf(v);
}

// ---- dtype detector: fp32 N(0,1) words have exponent in [87,132] -------
__global__ void kdetect(const unsigned int* __restrict__ z, int* __restrict__ flag) {
  const int t = threadIdx.x;
  __shared__ int cnt[4];
  unsigned int u = z[t];
  int e = (u >> 23) & 0xFF;
  int sane = (e >= 87 && e <= 132) ? 1 : 0;
  unsigned long long b = __ballot(sane);
  if ((t & 63) == 0) cnt[t >> 6] = __popcll(b);
  __syncthreads();
  if (t == 0) flag[0] = ((cnt[0] + cnt[1] + cnt[2] + cnt[3]) >= 128) ? 1 : 0;
}

// ---- weight prep: fragment-ordered bf16 copies -------------------------
// out[((ks*8+nf)*64 + lane)*8 + e] = bf16( W[(nf*16+l16)*128 + ks*32 + quad*8 + e] )
__global__ void kprep(const void* __restrict__ Wa1, const void* __restrict__ Wa2,
                      const void* __restrict__ Wb1, const void* __restrict__ Wb2,
                      const void* __restrict__ Wg,  const void* __restrict__ Wout,
                      ushort_t* __restrict__ wp, const int* __restrict__ flag)
{
  const int isf32 = *flag;
  const void* src;
  switch (blockIdx.x) {
    case 0: src = Wa1; break;
    case 1: src = Wa2; break;
    case 2: src = Wb1; break;
    case 3: src = Wb2; break;
    case 4: src = Wg;  break;
    default: src = Wout; break;
  }
  ushort_t* dst = wp + (size_t)blockIdx.x * WSZ;
  for (int c = threadIdx.x; c < 2048; c += 256) {
    int ks = c >> 9, nf = (c >> 6) & 7, lane = c & 63;
    int quad = lane >> 4, l16 = lane & 15;
    size_t sidx = (size_t)(nf*16 + l16)*128 + ks*32 + quad*8;
    float f[8]; load8f(src, sidx, isf32, f);
    *(uint4*)(dst + (size_t)c*8) = pack8(f);
  }
}

// ---------------- K1: fused LN(z) + 5 projections -----------------------
// zs: 128x128 bf16 tile, XOR-swizzled 16B chunks: phys_chunk = g_chunk ^ (row&7)
// tb: 64x136 bf16 transpose buffer (half of the 128 channels at a time)

__device__ __forceinline__ void do_pair(const ushort_t* zs, ushort_t* tb,
    const ushort_t* __restrict__ W1p, const ushort_t* __restrict__ W2p,
    ushort_t* __restrict__ dst, int R0)
{
  const int t = threadIdx.x;
  const int wave = t >> 6, lane = t & 63;
  const int quad = lane >> 4, l16 = lane & 15;
  f32x4 acc1[2][8], acc2[2][8];
  const f32x4 z4 = {0.f, 0.f, 0.f, 0.f};
#pragma unroll
  for (int mf = 0; mf < 2; ++mf)
#pragma unroll
    for (int nf = 0; nf < 8; ++nf) { acc1[mf][nf] = z4; acc2[mf][nf] = z4; }

#pragma unroll
  for (int ks = 0; ks < 4; ++ks) {
    bf16x8 af[2];
#pragma unroll
    for (int mf = 0; mf < 2; ++mf) {
      int row = wave*32 + mf*16 + l16;
      int ph = (ks*4 + quad) ^ (row & 7);
      af[mf] = *(const bf16x8*)(zs + row*128 + ph*8);
    }
#pragma unroll
    for (int nf = 0; nf < 8; ++nf) {
      size_t foff = (size_t)(((ks*8 + nf)*64 + lane)) * 8;   // coalesced 16B/lane
      bf16x8 b1 = *(const bf16x8*)(W1p + foff);
      bf16x8 b2 = *(const bf16x8*)(W2p + foff);
#pragma unroll
      for (int mf = 0; mf < 2; ++mf) {
        acc1[mf][nf] = __builtin_amdgcn_mfma_f32_16x16x32_bf16(af[mf], b1, acc1[mf][nf], 0, 0, 0);
        acc2[mf][nf] = __builtin_amdgcn_mfma_f32_16x16x32_bf16(af[mf], b2, acc2[mf][nf], 0, 0, 0);
      }
    }
  }
  // epilogue: gate, transpose through LDS in two 64-channel halves, store [d][R]
#pragma unroll
  for (int half = 0; half < 2; ++half) {
#pragma unroll
    for (int mf = 0; mf < 2; ++mf)
#pragma unroll
      for (int nf4 = 0; nf4 < 4; ++nf4) {
        int nf = half*4 + nf4;
#pragma unroll
        for (int r = 0; r < 4; ++r) {
          int row = wave*32 + mf*16 + quad*4 + r;
          int col = nf4*16 + l16;
          float v = acc2[mf][nf][r] * sigmoidf_(acc1[mf][nf][r]);
          tb[col*136 + row] = f2bf(v);
        }
      }
    __syncthreads();
#pragma unroll
    for (int i = 0; i < 4; ++i) {
      int cid = t + i*256;           // 64 d x 16 row-chunks
      int dl = cid >> 4, rc = cid & 15;
      uint4 v = *(const uint4*)(tb + dl*136 + rc*8);
      *(uint4*)(dst + (size_t)(half*64 + dl)*NR + R0 + rc*8) = v;
    }
    __syncthreads();
  }
}

__device__ __forceinline__ void do_single(const ushort_t* zs,
    const ushort_t* __restrict__ Wgp, void* __restrict__ gout,
    ushort_t* __restrict__ g_t, int gIsWs, int R0, int isf32)
{
  const int t = threadIdx.x;
  const int wave = t >> 6, lane = t & 63;
  const int quad = lane >> 4, l16 = lane & 15;
  f32x4 acc[2][8];
  const f32x4 z4 = {0.f, 0.f, 0.f, 0.f};
#pragma unroll
  for (int mf = 0; mf < 2; ++mf)
#pragma unroll
    for (int nf = 0; nf < 8; ++nf) acc[mf][nf] = z4;
#pragma unroll
  for (int ks = 0; ks < 4; ++ks) {
    bf16x8 af[2];
#pragma unroll
    for (int mf = 0; mf < 2; ++mf) {
      int row = wave*32 + mf*16 + l16;
      int ph = (ks*4 + quad) ^ (row & 7);
      af[mf] = *(const bf16x8*)(zs + row*128 + ph*8);
    }
#pragma unroll
    for (int nf = 0; nf < 8; ++nf) {
      size_t foff = (size_t)(((ks*8 + nf)*64 + lane)) * 8;
      bf16x8 b = *(const bf16x8*)(Wgp + foff);
#pragma unroll
      for (int mf = 0; mf < 2; ++mf)
        acc[mf][nf] = __builtin_amdgcn_mfma_f32_16x16x32_bf16(af[mf], b, acc[mf][nf], 0, 0, 0);
    }
  }
#pragma unroll
  for (int mf = 0; mf < 2; ++mf)
#pragma unroll
    for (int nf = 0; nf < 8; ++nf)
#pragma unroll
      for (int r = 0; r < 4; ++r) {
        int row = wave*32 + mf*16 + quad*4 + r;
        int col = nf*16 + l16;
        float v = sigmoidf_(acc[mf][nf][r]);
        size_t idx = (size_t)(R0 + row)*C + col;
        if (gIsWs) g_t[idx] = f2bf(v);
        else       store1(gout, idx, isf32, v);
      }
}

__global__ __launch_bounds__(256, 2)
void k1(const void* __restrict__ z, const void* __restrict__ gin,
        const void* __restrict__ bin, const ushort_t* __restrict__ wp,
        ushort_t* __restrict__ a_t, ushort_t* __restrict__ b_t,
        void* __restrict__ gout, ushort_t* __restrict__ g_t, int gIsWs,
        const int* __restrict__ flag)
{
  __shared__ ushort_t zs[128*128];
  __shared__ ushort_t tb[64*136];
  const int t = threadIdx.x;
  const int isf32 = *flag;
  const int R0 = blockIdx.x * 128;

  // stage z (swizzled, converted to bf16)
#pragma unroll
  for (int i = 0; i < 8; ++i) {
    int cid = t + i*256;
    int row = cid >> 4, p = cid & 15;
    int gch = p ^ (row & 7);
    float f[8];
    load8f(z, (size_t)(R0 + row)*C + gch*8, isf32, f);
    *(uint4*)(zs + row*128 + p*8) = pack8(f);
  }
  __syncthreads();

  // layernorm rows in-place (2 threads per row)
  {
    const int r = t >> 1, h = t & 1;
    uint4 q[8];
    float sum = 0.f, sq = 0.f;
#pragma unroll
    for (int j = 0; j < 8; ++j) {
      const int ph = (h*8 + j) ^ (r & 7);
      q[j] = *(const uint4*)(zs + r*128 + ph*8);
      float f[8]; unpack8(q[j], f);
#pragma unroll
      for (int e = 0; e < 8; ++e) { sum += f[e]; sq += f[e]*f[e]; }
    }
    sum += __shfl_xor(sum, 1);
    sq  += __shfl_xor(sq, 1);
    const float mu = sum * 0.0078125f;
    const float rstd = rsqrtf(sq * 0.0078125f - mu*mu + 1e-5f);
#pragma unroll
    for (int j = 0; j < 8; ++j) {
      const int g = h*8 + j;
      const int ph = g ^ (r & 7);
      float f[8], gm[8], bt[8];
      unpack8(q[j], f);
      load8f(gin, (size_t)g*8, isf32, gm);
      load8f(bin, (size_t)g*8, isf32, bt);
#pragma unroll
      for (int e = 0; e < 8; ++e) f[e] = (f[e] - mu) * rstd * gm[e] + bt[e];
      *(uint4*)(zs + r*128 + ph*8) = pack8(f);
    }
  }
  __syncthreads();

  do_pair(zs, tb, wp + 0*WSZ, wp + 1*WSZ, a_t, R0);
  do_pair(zs, tb, wp + 2*WSZ, wp + 3*WSZ, b_t, R0);
  do_single(zs, wp + 4*WSZ, gout, g_t, gIsWs, R0, isf32);
}

// ---------------- K2: s_d = A_d * B_d^T per channel ---------------------
__global__ __launch_bounds__(256, 2)
void k2(const ushort_t* __restrict__ a_t, const ushort_t* __restrict__ b_t,
        ushort_t* __restrict__ s_t)
{
  __shared__ ushort_t As[128*64];
  __shared__ ushort_t Bs[128*64];
  const int t = threadIdx.x;
  const int wave = t >> 6, lane = t & 63;
  const int quad = lane >> 4, l16 = lane & 15;
  const int wm = wave >> 1, wn = wave & 1;
  const int d = blockIdx.y;
  const int i0 = (blockIdx.x / 3) * 128, j0 = (blockIdx.x % 3) * 128;
  const size_t dbase = (size_t)d * NR;

  f32x4 acc[4][4];
  const f32x4 z4 = {0.f, 0.f, 0.f, 0.f};
#pragma unroll
  for (int mf = 0; mf < 4; ++mf)
#pragma unroll
    for (int nf = 0; nf < 4; ++nf) acc[mf][nf] = z4;

  for (int kt = 0; kt < 6; ++kt) {
    uint4 va[4], vb[4];
#pragma unroll
    for (int j = 0; j < 4; ++j) {
      int cid = t + j*256;                 // 1024 chunk-slots: 128 rows x 8 chunks
      int row = cid >> 3, c = cid & 7;
      va[j] = *(const uint4*)(a_t + dbase + (size_t)(i0 + row)*N + kt*64 + c*8);
      vb[j] = *(const uint4*)(b_t + dbase + (size_t)(j0 + row)*N + kt*64 + c*8);
    }
    __syncthreads();                       // previous iteration's reads complete
#pragma unroll
    for (int j = 0; j < 4; ++j) {
      int cid = t + j*256;
      int row = cid >> 3, c = cid & 7;
      int p = c ^ (row & 7);               // swizzle: conflict-free frag reads
      *(uint4*)(As + row*64 + p*8) = va[j];
      *(uint4*)(Bs + row*64 + p*8) = vb[j];
    }
    __syncthreads();                       // writes visible to all waves

#pragma unroll
    for (int ks = 0; ks < 2; ++ks) {
      bf16x8 af[4], bfr[4];
#pragma unroll
      for (int f = 0; f < 4; ++f) {
        int ra = wm*64 + f*16 + l16;
        int pa = (ks*4 + quad) ^ (ra & 7);
        af[f] = *(const bf16x8*)(As + ra*64 + pa*8);
        int rb = wn*64 + f*16 + l16;
        int pb = (ks*4 + quad) ^ (rb & 7);
        bfr[f] = *(const bf16x8*)(Bs + rb*64 + pb*8);
      }
#pragma unroll
      for (int mf = 0; mf < 4; ++mf)
#pragma unroll
        for (int nf = 0; nf < 4; ++nf)
          acc[mf][nf] = __builtin_amdgcn_mfma_f32_16x16x32_bf16(af[mf], bfr[nf], acc[mf][nf], 0, 0, 0);
    }
  }
#pragma unroll
  for (int mf = 0; mf < 4; ++mf)
#pragma unroll
    for (int nf = 0; nf < 4; ++nf)
#pragma unroll
      for (int r = 0; r < 4; ++r) {
        int row = wm*64 + mf*16 + quad*4 + r;
        int col = wn*64 + nf*16 + l16;
        s_t[dbase + (size_t)(i0 + row)*N + j0 + col] = f2bf(acc[mf][nf][r]);
      }
}

// ---------------- K3: out = g * (LN(s) @ Wout^T) ------------------------
__global__ __launch_bounds__(256, 3)
void k3(const ushort_t* __restrict__ s_t, const void* __restrict__ gno,
        const void* __restrict__ bno, const ushort_t* __restrict__ wp,
        void* __restrict__ io, const ushort_t* __restrict__ g_t, int gIsWs,
        const int* __restrict__ flag)
{
  __shared__ ushort_t ss[128*136];
  const int t = threadIdx.x;
  const int isf32 = *flag;
  const int wave = t >> 6, lane = t & 63;
  const int quad = lane >> 4, l16 = lane & 15;
  const int R0 = blockIdx.x * 128;
  const ushort_t* Woutp = wp + 5*WSZ;

  // stage s tile [d][R] -> LDS [R][d] via 8x8 register transpose
  {
    const int dg = t >> 4, rg = t & 15;
    const int d0 = dg * 8;
    uint4 v[8];
#pragma unroll
    for (int dd = 0; dd < 8; ++dd)
      v[dd] = *(const uint4*)(s_t + (size_t)(d0 + dd)*NR + R0 + rg*8);
    const ushort_t* sv = (const ushort_t*)v;
#pragma unroll
    for (int rr0 = 0; rr0 < 8; ++rr0) {
      int rr = (rr0 + (t & 7)) & 7;          // lane stagger: kills bank conflicts
      ushort_t w[8];
#pragma unroll
      for (int dd = 0; dd < 8; ++dd) w[dd] = sv[dd*8 + rr];
      *(uint4*)(ss + (rg*8 + rr)*136 + d0) = *(const uint4*)w;
    }
  }
  __syncthreads();

  // layernorm over d (2 threads per row)
  {
    const int r = t >> 1, h = t & 1;
    uint4 q[8];
    float sum = 0.f, sq = 0.f;
#pragma unroll
    for (int j = 0; j < 8; ++j) {
      q[j] = *(const uint4*)(ss + r*136 + (h*8 + j)*8);
      float f[8]; unpack8(q[j], f);
#pragma unroll
      for (int e = 0; e < 8; ++e) { sum += f[e]; sq += f[e]*f[e]; }
    }
    sum += __shfl_xor(sum, 1);
    sq  += __shfl_xor(sq, 1);
    const float mu = sum * 0.0078125f;
    const float rstd = rsqrtf(sq * 0.0078125f - mu*mu + 1e-5f);
#pragma unroll
    for (int j = 0; j < 8; ++j) {
      const int g = h*8 + j;
      float f[8], gm[8], bt[8];
      unpack8(q[j], f);
      load8f(gno, (size_t)g*8, isf32, gm);
      load8f(bno, (size_t)g*8, isf32, bt);
#pragma unroll
      for (int e = 0; e < 8; ++e) f[e] = (f[e] - mu) * rstd * gm[e] + bt[e];
      *(uint4*)(ss + r*136 + g*8) = pack8(f);
    }
  }
  __syncthreads();   // LN writes visible before GEMM fragment reads

  f32x4 acc[2][8];
  const f32x4 z4 = {0.f, 0.f, 0.f, 0.f};
#pragma unroll
  for (int mf = 0; mf < 2; ++mf)
#pragma unroll
    for (int nf = 0; nf < 8; ++nf) acc[mf][nf] = z4;
#pragma unroll
  for (int ks = 0; ks < 4; ++ks) {
    bf16x8 af[2];
#pragma unroll
    for (int mf = 0; mf < 2; ++mf) {
      int row = wave*32 + mf*16 + l16;
      af[mf] = *(const bf16x8*)(ss + row*136 + (ks*4 + quad)*8);
    }
#pragma unroll
    for (int nf = 0; nf < 8; ++nf) {
      size_t foff = (size_t)(((ks*8 + nf)*64 + lane)) * 8;
      bf16x8 b = *(const bf16x8*)(Woutp + foff);
#pragma unroll
      for (int mf = 0; mf < 2; ++mf)
        acc[mf][nf] = __builtin_amdgcn_mfma_f32_16x16x32_bf16(af[mf], b, acc[mf][nf], 0, 0, 0);
    }
  }
  __syncthreads();   // all fragment reads complete before h write-back

#pragma unroll
  for (int mf = 0; mf < 2; ++mf)
#pragma unroll
    for (int nf = 0; nf < 8; ++nf)
#pragma unroll
      for (int r = 0; r < 4; ++r) {
        int row = wave*32 + mf*16 + quad*4 + r;
        int col = nf*16 + l16;
        ss[row*136 + col] = f2bf(acc[mf][nf][r]);
      }
  __syncthreads();

  // gated store: out = g * h, fully vectorized
#pragma unroll
  for (int i = 0; i < 8; ++i) {
    int cid = t + i*256;
    int row = cid >> 4, ch = cid & 15;
    size_t idx = (size_t)(R0 + row)*C + ch*8;
    float gf[8], hf[8], of[8];
    if (gIsWs) unpack8(*(const uint4*)(g_t + idx), gf);
    else       load8f(io, idx, isf32, gf);
    unpack8(*(const uint4*)(ss + row*136 + ch*8), hf);
#pragma unroll
    for (int e = 0; e < 8; ++e) of[e] = gf[e] * hf[e];
    store8(io, idx, isf32, of);
  }
}

extern "C" void kernel_launch(void* const* d_in, const int* in_sizes, int n_in,
                              void* d_out, int out_size, void* d_ws, size_t ws_size,
                              hipStream_t stream) {
  (void)in_sizes; (void)n_in; (void)out_size;
  const void* z    = d_in[0];
  const void* gin  = d_in[1];
  const void* bin  = d_in[2];
  const void* gno  = d_in[3];
  const void* bno  = d_in[4];
  const void* Wa1  = d_in[5];
  const void* Wa2  = d_in[6];
  const void* Wb1  = d_in[7];
  const void* Wb2  = d_in[8];
  const void* Wg   = d_in[9];
  const void* Wout = d_in[10];

  int* flag     = (int*)d_ws;                                  // 256 B
  ushort_t* wp  = (ushort_t*)((char*)d_ws + 256);              // 6 x 32 KB
  ushort_t* a_t = wp + (size_t)6*WSZ;                          // [128][NR] bf16
  ushort_t* b_t = a_t + (size_t)NR * C;
  ushort_t* s_t = b_t + (size_t)NR * C;
  ushort_t* g_t = s_t + (size_t)NR * C;
  size_t need_g = 256 + (size_t)6*WSZ*2 + (size_t)4*NR*C*2;
  int gIsWs = (ws_size >= need_g) ? 1 : 0;

  kdetect<<<1, 256, 0, stream>>>((const unsigned int*)z, flag);
  kprep<<<6, 256, 0, stream>>>(Wa1, Wa2, Wb1, Wb2, Wg, Wout, wp, flag);
  k1<<<NR/128, 256, 0, stream>>>(z, gin, bin, wp, a_t, b_t, d_out, g_t, gIsWs, flag);
  k2<<<dim3(9, 128), 256, 0, stream>>>(a_t, b_t, s_t);
  k3<<<NR/128, 256, 0, stream>>>(s_t, gno, bno, wp, d_out, g_t, gIsWs, flag);
}

// Round 5
// 429.861 us; speedup vs baseline: 1.4245x; 1.0729x over previous
//
#include <hip/hip_runtime.h>
#include <stdint.h>

#define N 384
#define NR (N*N)        // 147456
#define C 128
#define WSZ 16384       // 128x128 elements per weight

typedef unsigned short ushort_t;
typedef __attribute__((ext_vector_type(8))) short bf16x8;
typedef __attribute__((ext_vector_type(4))) float f32x4;

__device__ __forceinline__ float bf2f(ushort_t u) {
  union { unsigned int i; float f; } v; v.i = ((unsigned int)u) << 16; return v.f;
}
__device__ __forceinline__ ushort_t f2bf(float f) {
  union { float f; unsigned int i; } v; v.f = f;
  unsigned int u = v.i + 0x7FFF + ((v.i >> 16) & 1);
  return (ushort_t)(u >> 16);
}
__device__ __forceinline__ float sigmoidf_(float x) {
  return 1.0f / (1.0f + __expf(-x));
}
__device__ __forceinline__ void unpack8(uint4 q, float f[8]) {
  const unsigned int* w = (const unsigned int*)&q;
#pragma unroll
  for (int e = 0; e < 4; ++e) {
    f[2*e]   = bf2f((ushort_t)(w[e] & 0xffffu));
    f[2*e+1] = bf2f((ushort_t)(w[e] >> 16));
  }
}
__device__ __forceinline__ uint4 pack8(const float f[8]) {
  uint4 q;
  unsigned int* w = (unsigned int*)&q;
#pragma unroll
  for (int e = 0; e < 4; ++e)
    w[e] = (unsigned int)f2bf(f[2*e]) | ((unsigned int)f2bf(f[2*e+1]) << 16);
  return q;
}

// ---- dtype-dual IO helpers (isf32 is wave-uniform) ---------------------
__device__ __forceinline__ void load8f(const void* p, size_t idx, int isf32, float f[8]) {
  if (isf32) {
    const float* q = (const float*)p + idx;
    const float4 a = ((const float4*)q)[0];
    const float4 b = ((const float4*)q)[1];
    f[0]=a.x; f[1]=a.y; f[2]=a.z; f[3]=a.w;
    f[4]=b.x; f[5]=b.y; f[6]=b.z; f[7]=b.w;
  } else {
    unpack8(*(const uint4*)((const ushort_t*)p + idx), f);
  }
}
__device__ __forceinline__ void store8(void* p, size_t idx, int isf32, const float f[8]) {
  if (isf32) {
    float* q = (float*)p + idx;
    ((float4*)q)[0] = make_float4(f[0], f[1], f[2], f[3]);
    ((float4*)q)[1] = make_float4(f[4], f[5], f[6], f[7]);
  } else {
    *(uint4*)((ushort_t*)p + idx) = pack8(f);
  }
}
__device__ __forceinline__ void store1(void* p, size_t idx, int isf32, float v) {
  if (isf32) ((float*)p)[idx] = v;
  else       ((ushort_t*)p)[idx] = f2bf(v);
}

// ---- dtype detector: fp32 N(0,1) words have exponent in [87,132] -------
__global__ void kdetect(const unsigned int* __restrict__ z, int* __restrict__ flag) {
  const int t = threadIdx.x;
  __shared__ int cnt[4];
  unsigned int u = z[t];
  int e = (u >> 23) & 0xFF;
  int sane = (e >= 87 && e <= 132) ? 1 : 0;
  unsigned long long b = __ballot(sane);
  if ((t & 63) == 0) cnt[t >> 6] = __popcll(b);
  __syncthreads();
  if (t == 0) flag[0] = ((cnt[0] + cnt[1] + cnt[2] + cnt[3]) >= 128) ? 1 : 0;
}

// ---- weight prep: fragment-ordered bf16 copies -------------------------
// out[((ks*8+nf)*64 + lane)*8 + e] = bf16( W[(nf*16+l16)*128 + ks*32 + quad*8 + e] )
__global__ void kprep(const void* __restrict__ Wa1, const void* __restrict__ Wa2,
                      const void* __restrict__ Wb1, const void* __restrict__ Wb2,
                      const void* __restrict__ Wg,  const void* __restrict__ Wout,
                      ushort_t* __restrict__ wp, const int* __restrict__ flag)
{
  const int isf32 = *flag;
  const void* src;
  switch (blockIdx.x) {
    case 0: src = Wa1; break;
    case 1: src = Wa2; break;
    case 2: src = Wb1; break;
    case 3: src = Wb2; break;
    case 4: src = Wg;  break;
    default: src = Wout; break;
  }
  ushort_t* dst = wp + (size_t)blockIdx.x * WSZ;
  for (int c = threadIdx.x; c < 2048; c += 256) {
    int ks = c >> 9, nf = (c >> 6) & 7, lane = c & 63;
    int quad = lane >> 4, l16 = lane & 15;
    size_t sidx = (size_t)(nf*16 + l16)*128 + ks*32 + quad*8;
    float f[8]; load8f(src, sidx, isf32, f);
    *(uint4*)(dst + (size_t)c*8) = pack8(f);
  }
}

// ---------------- K1: fused LN(z) + 5 projections (register LN) ---------
// Block = 64 rows, 4 waves as (rg = row-group of 32, ch = col-half of 64).
// A-fragments built in registers from global z + in-register LN (shfl over
// quad axis: lanes {l16,+16,+32,+48} hold disjoint k-chunks of one row).
// Only LDS use: tb transpose buffer for the [R][d]->[d][R] a/b stores.
__global__ __launch_bounds__(256, 3)
void k1(const void* __restrict__ z, const void* __restrict__ gin,
        const void* __restrict__ bin, const ushort_t* __restrict__ wp,
        ushort_t* __restrict__ a_t, ushort_t* __restrict__ b_t,
        void* __restrict__ gout, ushort_t* __restrict__ g_t, int gIsWs,
        const int* __restrict__ flag)
{
  __shared__ ushort_t tb[128*72];      // 18 KB: 128 d x 64 rows (+pad to 72)
  const int t = threadIdx.x;
  const int isf32 = *flag;
  const int wave = t >> 6, lane = t & 63;
  const int quad = lane >> 4, l16 = lane & 15;
  const int rg = wave >> 1, ch = wave & 1;
  const int R0 = blockIdx.x * 64;
  const f32x4 z4 = {0.f, 0.f, 0.f, 0.f};

  // ---- A-fragments + in-register layernorm
  bf16x8 af[2][4];
#pragma unroll
  for (int mf = 0; mf < 2; ++mf) {
    const int row = R0 + rg*32 + mf*16 + l16;
    float x[4][8];
    float s = 0.f, q = 0.f;
#pragma unroll
    for (int ks = 0; ks < 4; ++ks) {
      load8f(z, (size_t)row*C + ks*32 + quad*8, isf32, x[ks]);
#pragma unroll
      for (int e = 0; e < 8; ++e) { s += x[ks][e]; q += x[ks][e]*x[ks][e]; }
    }
    s += __shfl_xor(s, 16); s += __shfl_xor(s, 32);
    q += __shfl_xor(q, 16); q += __shfl_xor(q, 32);
    const float mu = s * 0.0078125f;
    const float rstd = rsqrtf(q * 0.0078125f - mu*mu + 1e-5f);
#pragma unroll
    for (int ks = 0; ks < 4; ++ks) {
      float ga[8], be[8];
      load8f(gin, (size_t)(ks*32 + quad*8), isf32, ga);
      load8f(bin, (size_t)(ks*32 + quad*8), isf32, be);
      union { alignas(16) ushort_t w[8]; bf16x8 v; } u;
#pragma unroll
      for (int e = 0; e < 8; ++e)
        u.w[e] = f2bf((x[ks][e] - mu) * rstd * ga[e] + be[e]);
      af[mf][ks] = u.v;
    }
  }

  // ---- gated pair projection: dst[d][R] = sig(z@W1^T) * (z@W2^T)
  auto pair = [&](const ushort_t* W1p, const ushort_t* W2p, ushort_t* dst) {
    f32x4 a1[2][4], a2[2][4];
#pragma unroll
    for (int mf = 0; mf < 2; ++mf)
#pragma unroll
      for (int nf = 0; nf < 4; ++nf) { a1[mf][nf] = z4; a2[mf][nf] = z4; }
#pragma unroll
    for (int ks = 0; ks < 4; ++ks)
#pragma unroll
      for (int nf = 0; nf < 4; ++nf) {
        const size_t foff = (size_t)((ks*8 + ch*4 + nf)*64 + lane) * 8;
        bf16x8 b1 = *(const bf16x8*)(W1p + foff);
        bf16x8 b2 = *(const bf16x8*)(W2p + foff);
#pragma unroll
        for (int mf = 0; mf < 2; ++mf) {
          a1[mf][nf] = __builtin_amdgcn_mfma_f32_16x16x32_bf16(af[mf][ks], b1, a1[mf][nf], 0, 0, 0);
          a2[mf][nf] = __builtin_amdgcn_mfma_f32_16x16x32_bf16(af[mf][ks], b2, a2[mf][nf], 0, 0, 0);
        }
      }
#pragma unroll
    for (int mf = 0; mf < 2; ++mf)
#pragma unroll
      for (int nf = 0; nf < 4; ++nf)
#pragma unroll
        for (int r = 0; r < 4; ++r) {
          int rowl = rg*32 + mf*16 + quad*4 + r;       // 0..64
          int col  = ch*64 + nf*16 + l16;              // 0..128 (the d index)
          tb[col*72 + rowl] = f2bf(a2[mf][nf][r] * sigmoidf_(a1[mf][nf][r]));
        }
    __syncthreads();
#pragma unroll
    for (int i = 0; i < 4; ++i) {
      int cid = t + i*256, dl = cid >> 3, rc = cid & 7;  // 128 d x 8 chunks
      uint4 v = *(const uint4*)(tb + dl*72 + rc*8);
      *(uint4*)(dst + (size_t)dl*NR + R0 + rc*8) = v;
    }
    __syncthreads();
  };
  pair(wp + 0*WSZ, wp + 1*WSZ, a_t);
  pair(wp + 2*WSZ, wp + 3*WSZ, b_t);

  // ---- g = sigmoid(z@Wg^T), natural [R][d] layout
  {
    const ushort_t* Wgp = wp + 4*WSZ;
    f32x4 ag[2][4];
#pragma unroll
    for (int mf = 0; mf < 2; ++mf)
#pragma unroll
      for (int nf = 0; nf < 4; ++nf) ag[mf][nf] = z4;
#pragma unroll
    for (int ks = 0; ks < 4; ++ks)
#pragma unroll
      for (int nf = 0; nf < 4; ++nf) {
        const size_t foff = (size_t)((ks*8 + ch*4 + nf)*64 + lane) * 8;
        bf16x8 b = *(const bf16x8*)(Wgp + foff);
#pragma unroll
        for (int mf = 0; mf < 2; ++mf)
          ag[mf][nf] = __builtin_amdgcn_mfma_f32_16x16x32_bf16(af[mf][ks], b, ag[mf][nf], 0, 0, 0);
      }
#pragma unroll
    for (int mf = 0; mf < 2; ++mf)
#pragma unroll
      for (int nf = 0; nf < 4; ++nf)
#pragma unroll
        for (int r = 0; r < 4; ++r) {
          int row = R0 + rg*32 + mf*16 + quad*4 + r;
          int col = ch*64 + nf*16 + l16;
          float v = sigmoidf_(ag[mf][nf][r]);
          size_t idx = (size_t)row*C + col;
          if (gIsWs) g_t[idx] = f2bf(v);
          else       store1(gout, idx, isf32, v);
        }
  }
}

// ---------------- K2: s_d = A_d * B_d^T per channel ---------------------
__global__ __launch_bounds__(256, 2)
void k2(const ushort_t* __restrict__ a_t, const ushort_t* __restrict__ b_t,
        ushort_t* __restrict__ s_t)
{
  __shared__ ushort_t As[128*64];
  __shared__ ushort_t Bs[128*64];
  const int t = threadIdx.x;
  const int wave = t >> 6, lane = t & 63;
  const int quad = lane >> 4, l16 = lane & 15;
  const int wm = wave >> 1, wn = wave & 1;
  const int d = blockIdx.y;
  const int i0 = (blockIdx.x / 3) * 128, j0 = (blockIdx.x % 3) * 128;
  const size_t dbase = (size_t)d * NR;

  f32x4 acc[4][4];
  const f32x4 z4 = {0.f, 0.f, 0.f, 0.f};
#pragma unroll
  for (int mf = 0; mf < 4; ++mf)
#pragma unroll
    for (int nf = 0; nf < 4; ++nf) acc[mf][nf] = z4;

  for (int kt = 0; kt < 6; ++kt) {
    uint4 va[4], vb[4];
#pragma unroll
    for (int j = 0; j < 4; ++j) {
      int cid = t + j*256;                 // 1024 chunk-slots: 128 rows x 8 chunks
      int row = cid >> 3, c = cid & 7;
      va[j] = *(const uint4*)(a_t + dbase + (size_t)(i0 + row)*N + kt*64 + c*8);
      vb[j] = *(const uint4*)(b_t + dbase + (size_t)(j0 + row)*N + kt*64 + c*8);
    }
    __syncthreads();                       // previous iteration's reads complete
#pragma unroll
    for (int j = 0; j < 4; ++j) {
      int cid = t + j*256;
      int row = cid >> 3, c = cid & 7;
      int p = c ^ (row & 7);               // swizzle: conflict-free frag reads
      *(uint4*)(As + row*64 + p*8) = va[j];
      *(uint4*)(Bs + row*64 + p*8) = vb[j];
    }
    __syncthreads();                       // writes visible to all waves

#pragma unroll
    for (int ks = 0; ks < 2; ++ks) {
      bf16x8 af[4], bfr[4];
#pragma unroll
      for (int f = 0; f < 4; ++f) {
        int ra = wm*64 + f*16 + l16;
        int pa = (ks*4 + quad) ^ (ra & 7);
        af[f] = *(const bf16x8*)(As + ra*64 + pa*8);
        int rb = wn*64 + f*16 + l16;
        int pb = (ks*4 + quad) ^ (rb & 7);
        bfr[f] = *(const bf16x8*)(Bs + rb*64 + pb*8);
      }
#pragma unroll
      for (int mf = 0; mf < 4; ++mf)
#pragma unroll
        for (int nf = 0; nf < 4; ++nf)
          acc[mf][nf] = __builtin_amdgcn_mfma_f32_16x16x32_bf16(af[mf], bfr[nf], acc[mf][nf], 0, 0, 0);
    }
  }
#pragma unroll
  for (int mf = 0; mf < 4; ++mf)
#pragma unroll
    for (int nf = 0; nf < 4; ++nf)
#pragma unroll
      for (int r = 0; r < 4; ++r) {
        int row = wm*64 + mf*16 + quad*4 + r;
        int col = wn*64 + nf*16 + l16;
        s_t[dbase + (size_t)(i0 + row)*N + j0 + col] = f2bf(acc[mf][nf][r]);
      }
}

// ---------------- K3: out = g * (LN(s) @ Wout^T) ------------------------
__global__ __launch_bounds__(256, 3)
void k3(const ushort_t* __restrict__ s_t, const void* __restrict__ gno,
        const void* __restrict__ bno, const ushort_t* __restrict__ wp,
        void* __restrict__ io, const ushort_t* __restrict__ g_t, int gIsWs,
        const int* __restrict__ flag)
{
  __shared__ ushort_t ss[128*136];
  const int t = threadIdx.x;
  const int isf32 = *flag;
  const int wave = t >> 6, lane = t & 63;
  const int quad = lane >> 4, l16 = lane & 15;
  const int R0 = blockIdx.x * 128;
  const ushort_t* Woutp = wp + 5*WSZ;

  // stage s tile [d][R] -> LDS [R][d] via 8x8 register transpose
  {
    const int dg = t >> 4, rg = t & 15;
    const int d0 = dg * 8;
    uint4 v[8];
#pragma unroll
    for (int dd = 0; dd < 8; ++dd)
      v[dd] = *(const uint4*)(s_t + (size_t)(d0 + dd)*NR + R0 + rg*8);
    const ushort_t* sv = (const ushort_t*)v;
#pragma unroll
    for (int rr0 = 0; rr0 < 8; ++rr0) {
      int rr = (rr0 + (t & 7)) & 7;          // lane stagger: kills bank conflicts
      ushort_t w[8];
#pragma unroll
      for (int dd = 0; dd < 8; ++dd) w[dd] = sv[dd*8 + rr];
      *(uint4*)(ss + (rg*8 + rr)*136 + d0) = *(const uint4*)w;
    }
  }
  __syncthreads();

  // layernorm over d (2 threads per row)
  {
    const int r = t >> 1, h = t & 1;
    uint4 q[8];
    float sum = 0.f, sq = 0.f;
#pragma unroll
    for (int j = 0; j < 8; ++j) {
      q[j] = *(const uint4*)(ss + r*136 + (h*8 + j)*8);
      float f[8]; unpack8(q[j], f);
#pragma unroll
      for (int e = 0; e < 8; ++e) { sum += f[e]; sq += f[e]*f[e]; }
    }
    sum += __shfl_xor(sum, 1);
    sq  += __shfl_xor(sq, 1);
    const float mu = sum * 0.0078125f;
    const float rstd = rsqrtf(sq * 0.0078125f - mu*mu + 1e-5f);
#pragma unroll
    for (int j = 0; j < 8; ++j) {
      const int g = h*8 + j;
      float f[8], gm[8], bt[8];
      unpack8(q[j], f);
      load8f(gno, (size_t)g*8, isf32, gm);
      load8f(bno, (size_t)g*8, isf32, bt);
#pragma unroll
      for (int e = 0; e < 8; ++e) f[e] = (f[e] - mu) * rstd * gm[e] + bt[e];
      *(uint4*)(ss + r*136 + g*8) = pack8(f);
    }
  }
  __syncthreads();   // LN writes visible before GEMM fragment reads

  f32x4 acc[2][8];
  const f32x4 z4 = {0.f, 0.f, 0.f, 0.f};
#pragma unroll
  for (int mf = 0; mf < 2; ++mf)
#pragma unroll
    for (int nf = 0; nf < 8; ++nf) acc[mf][nf] = z4;
#pragma unroll
  for (int ks = 0; ks < 4; ++ks) {
    bf16x8 af[2];
#pragma unroll
    for (int mf = 0; mf < 2; ++mf) {
      int row = wave*32 + mf*16 + l16;
      af[mf] = *(const bf16x8*)(ss + row*136 + (ks*4 + quad)*8);
    }
#pragma unroll
    for (int nf = 0; nf < 8; ++nf) {
      size_t foff = (size_t)(((ks*8 + nf)*64 + lane)) * 8;
      bf16x8 b = *(const bf16x8*)(Woutp + foff);
#pragma unroll
      for (int mf = 0; mf < 2; ++mf)
        acc[mf][nf] = __builtin_amdgcn_mfma_f32_16x16x32_bf16(af[mf], b, acc[mf][nf], 0, 0, 0);
    }
  }
  __syncthreads();   // all fragment reads complete before h write-back

#pragma unroll
  for (int mf = 0; mf < 2; ++mf)
#pragma unroll
    for (int nf = 0; nf < 8; ++nf)
#pragma unroll
      for (int r = 0; r < 4; ++r) {
        int row = wave*32 + mf*16 + quad*4 + r;
        int col = nf*16 + l16;
        ss[row*136 + col] = f2bf(acc[mf][nf][r]);
      }
  __syncthreads();

  // gated store: out = g * h, fully vectorized
#pragma unroll
  for (int i = 0; i < 8; ++i) {
    int cid = t + i*256;
    int row = cid >> 4, ch = cid & 15;
    size_t idx = (size_t)(R0 + row)*C + ch*8;
    float gf[8], hf[8], of[8];
    if (gIsWs) unpack8(*(const uint4*)(g_t + idx), gf);
    else       load8f(io, idx, isf32, gf);
    unpack8(*(const uint4*)(ss + row*136 + ch*8), hf);
#pragma unroll
    for (int e = 0; e < 8; ++e) of[e] = gf[e] * hf[e];
    store8(io, idx, isf32, of);
  }
}

extern "C" void kernel_launch(void* const* d_in, const int* in_sizes, int n_in,
                              void* d_out, int out_size, void* d_ws, size_t ws_size,
                              hipStream_t stream) {
  (void)in_sizes; (void)n_in; (void)out_size;
  const void* z    = d_in[0];
  const void* gin  = d_in[1];
  const void* bin  = d_in[2];
  const void* gno  = d_in[3];
  const void* bno  = d_in[4];
  const void* Wa1  = d_in[5];
  const void* Wa2  = d_in[6];
  const void* Wb1  = d_in[7];
  const void* Wb2  = d_in[8];
  const void* Wg   = d_in[9];
  const void* Wout = d_in[10];

  int* flag     = (int*)d_ws;                                  // 256 B
  ushort_t* wp  = (ushort_t*)((char*)d_ws + 256);              // 6 x 32 KB
  ushort_t* a_t = wp + (size_t)6*WSZ;                          // [128][NR] bf16
  ushort_t* b_t = a_t + (size_t)NR * C;
  ushort_t* s_t = b_t + (size_t)NR * C;
  ushort_t* g_t = s_t + (size_t)NR * C;
  size_t need_g = 256 + (size_t)6*WSZ*2 + (size_t)4*NR*C*2;
  int gIsWs = (ws_size >= need_g) ? 1 : 0;

  kdetect<<<1, 256, 0, stream>>>((const unsigned int*)z, flag);
  kprep<<<6, 256, 0, stream>>>(Wa1, Wa2, Wb1, Wb2, Wg, Wout, wp, flag);
  k1<<<NR/64, 256, 0, stream>>>(z, gin, bin, wp, a_t, b_t, d_out, g_t, gIsWs, flag);
  k2<<<dim3(9, 128), 256, 0, stream>>>(a_t, b_t, s_t);
  k3<<<NR/128, 256, 0, stream>>>(s_t, gno, bno, wp, d_out, g_t, gIsWs, flag);
}

// Round 6
// 416.309 us; speedup vs baseline: 1.4708x; 1.0326x over previous
//
#include <hip/hip_runtime.h>
#include <stdint.h>

#define N 384
#define NR (N*N)        // 147456
#define PL (NR + 64)    // padded plane stride: 2305 cache lines, kills L2 set aliasing
#define C 128
#define WSZ 16384       // 128x128 elements per weight

typedef unsigned short ushort_t;
typedef __attribute__((ext_vector_type(8))) short bf16x8;
typedef __attribute__((ext_vector_type(4))) float f32x4;

__device__ __forceinline__ float bf2f(ushort_t u) {
  union { unsigned int i; float f; } v; v.i = ((unsigned int)u) << 16; return v.f;
}
__device__ __forceinline__ ushort_t f2bf(float f) {
  union { float f; unsigned int i; } v; v.f = f;
  unsigned int u = v.i + 0x7FFF + ((v.i >> 16) & 1);
  return (ushort_t)(u >> 16);
}
__device__ __forceinline__ float sigmoidf_(float x) {
  return 1.0f / (1.0f + __expf(-x));
}
__device__ __forceinline__ void unpack8(uint4 q, float f[8]) {
  const unsigned int* w = (const unsigned int*)&q;
#pragma unroll
  for (int e = 0; e < 4; ++e) {
    f[2*e]   = bf2f((ushort_t)(w[e] & 0xffffu));
    f[2*e+1] = bf2f((ushort_t)(w[e] >> 16));
  }
}
__device__ __forceinline__ uint4 pack8(const float f[8]) {
  uint4 q;
  unsigned int* w = (unsigned int*)&q;
#pragma unroll
  for (int e = 0; e < 4; ++e)
    w[e] = (unsigned int)f2bf(f[2*e]) | ((unsigned int)f2bf(f[2*e+1]) << 16);
  return q;
}

// ---- dtype-dual IO helpers (isf32 is wave-uniform) ---------------------
__device__ __forceinline__ void load8f(const void* p, size_t idx, int isf32, float f[8]) {
  if (isf32) {
    const float* q = (const float*)p + idx;
    const float4 a = ((const float4*)q)[0];
    const float4 b = ((const float4*)q)[1];
    f[0]=a.x; f[1]=a.y; f[2]=a.z; f[3]=a.w;
    f[4]=b.x; f[5]=b.y; f[6]=b.z; f[7]=b.w;
  } else {
    unpack8(*(const uint4*)((const ushort_t*)p + idx), f);
  }
}
__device__ __forceinline__ void store8(void* p, size_t idx, int isf32, const float f[8]) {
  if (isf32) {
    float* q = (float*)p + idx;
    ((float4*)q)[0] = make_float4(f[0], f[1], f[2], f[3]);
    ((float4*)q)[1] = make_float4(f[4], f[5], f[6], f[7]);
  } else {
    *(uint4*)((ushort_t*)p + idx) = pack8(f);
  }
}
__device__ __forceinline__ void store1(void* p, size_t idx, int isf32, float v) {
  if (isf32) ((float*)p)[idx] = v;
  else       ((ushort_t*)p)[idx] = f2bf(v);
}

// ---- dtype detector: fp32 N(0,1) words have exponent in [87,132] -------
__global__ void kdetect(const unsigned int* __restrict__ z, int* __restrict__ flag) {
  const int t = threadIdx.x;
  __shared__ int cnt[4];
  unsigned int u = z[t];
  int e = (u >> 23) & 0xFF;
  int sane = (e >= 87 && e <= 132) ? 1 : 0;
  unsigned long long b = __ballot(sane);
  if ((t & 63) == 0) cnt[t >> 6] = __popcll(b);
  __syncthreads();
  if (t == 0) flag[0] = ((cnt[0] + cnt[1] + cnt[2] + cnt[3]) >= 128) ? 1 : 0;
}

// ---- weight prep: fragment-ordered bf16 copies -------------------------
// out[((ks*8+nf)*64 + lane)*8 + e] = bf16( W[(nf*16+l16)*128 + ks*32 + quad*8 + e] )
__global__ void kprep(const void* __restrict__ Wa1, const void* __restrict__ Wa2,
                      const void* __restrict__ Wb1, const void* __restrict__ Wb2,
                      const void* __restrict__ Wg,  const void* __restrict__ Wout,
                      ushort_t* __restrict__ wp, const int* __restrict__ flag)
{
  const int isf32 = *flag;
  const void* src;
  switch (blockIdx.x) {
    case 0: src = Wa1; break;
    case 1: src = Wa2; break;
    case 2: src = Wb1; break;
    case 3: src = Wb2; break;
    case 4: src = Wg;  break;
    default: src = Wout; break;
  }
  ushort_t* dst = wp + (size_t)blockIdx.x * WSZ;
  for (int c = threadIdx.x; c < 2048; c += 256) {
    int ks = c >> 9, nf = (c >> 6) & 7, lane = c & 63;
    int quad = lane >> 4, l16 = lane & 15;
    size_t sidx = (size_t)(nf*16 + l16)*128 + ks*32 + quad*8;
    float f[8]; load8f(src, sidx, isf32, f);
    *(uint4*)(dst + (size_t)c*8) = pack8(f);
  }
}

// ---------------- K1: fused LN(z) + 5 projections (register LN) ---------
__global__ __launch_bounds__(256, 3)
void k1(const void* __restrict__ z, const void* __restrict__ gin,
        const void* __restrict__ bin, const ushort_t* __restrict__ wp,
        ushort_t* __restrict__ a_t, ushort_t* __restrict__ b_t,
        void* __restrict__ gout, ushort_t* __restrict__ g_t, int gIsWs,
        const int* __restrict__ flag)
{
  __shared__ ushort_t tb[128*72];      // 18 KB: 128 d x 64 rows (+pad to 72)
  const int t = threadIdx.x;
  const int isf32 = *flag;
  const int wave = t >> 6, lane = t & 63;
  const int quad = lane >> 4, l16 = lane & 15;
  const int rg = wave >> 1, ch = wave & 1;
  const int R0 = blockIdx.x * 64;
  const f32x4 z4 = {0.f, 0.f, 0.f, 0.f};

  // ---- A-fragments + in-register layernorm (stats on bf16-rounded z,
  //      matching the round-4 numeric path that gave absmax 0.0166)
  bf16x8 af[2][4];
#pragma unroll
  for (int mf = 0; mf < 2; ++mf) {
    const int row = R0 + rg*32 + mf*16 + l16;
    float x[4][8];
    float s = 0.f, q = 0.f;
#pragma unroll
    for (int ks = 0; ks < 4; ++ks) {
      load8f(z, (size_t)row*C + ks*32 + quad*8, isf32, x[ks]);
#pragma unroll
      for (int e = 0; e < 8; ++e) {
        x[ks][e] = bf2f(f2bf(x[ks][e]));
        s += x[ks][e]; q += x[ks][e]*x[ks][e];
      }
    }
    s += __shfl_xor(s, 16); s += __shfl_xor(s, 32);
    q += __shfl_xor(q, 16); q += __shfl_xor(q, 32);
    const float mu = s * 0.0078125f;
    const float rstd = rsqrtf(q * 0.0078125f - mu*mu + 1e-5f);
#pragma unroll
    for (int ks = 0; ks < 4; ++ks) {
      float ga[8], be[8];
      load8f(gin, (size_t)(ks*32 + quad*8), isf32, ga);
      load8f(bin, (size_t)(ks*32 + quad*8), isf32, be);
      union { alignas(16) ushort_t w[8]; bf16x8 v; } u;
#pragma unroll
      for (int e = 0; e < 8; ++e)
        u.w[e] = f2bf((x[ks][e] - mu) * rstd * ga[e] + be[e]);
      af[mf][ks] = u.v;
    }
  }

  // ---- gated pair projection: dst[d][R] = sig(z@W1^T) * (z@W2^T)
  auto pair = [&](const ushort_t* W1p, const ushort_t* W2p, ushort_t* dst) {
    f32x4 a1[2][4], a2[2][4];
#pragma unroll
    for (int mf = 0; mf < 2; ++mf)
#pragma unroll
      for (int nf = 0; nf < 4; ++nf) { a1[mf][nf] = z4; a2[mf][nf] = z4; }
#pragma unroll
    for (int ks = 0; ks < 4; ++ks)
#pragma unroll
      for (int nf = 0; nf < 4; ++nf) {
        const size_t foff = (size_t)((ks*8 + ch*4 + nf)*64 + lane) * 8;
        bf16x8 b1 = *(const bf16x8*)(W1p + foff);
        bf16x8 b2 = *(const bf16x8*)(W2p + foff);
#pragma unroll
        for (int mf = 0; mf < 2; ++mf) {
          a1[mf][nf] = __builtin_amdgcn_mfma_f32_16x16x32_bf16(af[mf][ks], b1, a1[mf][nf], 0, 0, 0);
          a2[mf][nf] = __builtin_amdgcn_mfma_f32_16x16x32_bf16(af[mf][ks], b2, a2[mf][nf], 0, 0, 0);
        }
      }
#pragma unroll
    for (int mf = 0; mf < 2; ++mf)
#pragma unroll
      for (int nf = 0; nf < 4; ++nf)
#pragma unroll
        for (int r = 0; r < 4; ++r) {
          int rowl = rg*32 + mf*16 + quad*4 + r;       // 0..64
          int col  = ch*64 + nf*16 + l16;              // 0..128 (the d index)
          tb[col*72 + rowl] = f2bf(a2[mf][nf][r] * sigmoidf_(a1[mf][nf][r]));
        }
    __syncthreads();
#pragma unroll
    for (int i = 0; i < 4; ++i) {
      int cid = t + i*256, dl = cid >> 3, rc = cid & 7;  // 128 d x 8 chunks
      uint4 v = *(const uint4*)(tb + dl*72 + rc*8);
      *(uint4*)(dst + (size_t)dl*PL + R0 + rc*8) = v;
    }
    __syncthreads();
  };
  pair(wp + 0*WSZ, wp + 1*WSZ, a_t);
  pair(wp + 2*WSZ, wp + 3*WSZ, b_t);

  // ---- g = sigmoid(z@Wg^T), natural [R][d] layout
  {
    const ushort_t* Wgp = wp + 4*WSZ;
    f32x4 ag[2][4];
#pragma unroll
    for (int mf = 0; mf < 2; ++mf)
#pragma unroll
      for (int nf = 0; nf < 4; ++nf) ag[mf][nf] = z4;
#pragma unroll
    for (int ks = 0; ks < 4; ++ks)
#pragma unroll
      for (int nf = 0; nf < 4; ++nf) {
        const size_t foff = (size_t)((ks*8 + ch*4 + nf)*64 + lane) * 8;
        bf16x8 b = *(const bf16x8*)(Wgp + foff);
#pragma unroll
        for (int mf = 0; mf < 2; ++mf)
          ag[mf][nf] = __builtin_amdgcn_mfma_f32_16x16x32_bf16(af[mf][ks], b, ag[mf][nf], 0, 0, 0);
      }
#pragma unroll
    for (int mf = 0; mf < 2; ++mf)
#pragma unroll
      for (int nf = 0; nf < 4; ++nf)
#pragma unroll
        for (int r = 0; r < 4; ++r) {
          int row = R0 + rg*32 + mf*16 + quad*4 + r;
          int col = ch*64 + nf*16 + l16;
          float v = sigmoidf_(ag[mf][nf][r]);
          size_t idx = (size_t)row*C + col;
          if (gIsWs) g_t[idx] = f2bf(v);
          else       store1(gout, idx, isf32, v);
        }
  }
}

// ---------------- K2: s_d = A_d * B_d^T per channel ---------------------
// 1D grid (1152); XCD-swizzle so the 9 tiles of one d share linear id mod 8
// (heuristic round-robin XCD assignment -> same-XCD L2 reuse of a/b planes).
__global__ __launch_bounds__(256, 2)
void k2(const ushort_t* __restrict__ a_t, const ushort_t* __restrict__ b_t,
        ushort_t* __restrict__ s_t)
{
  __shared__ ushort_t As[128*64];
  __shared__ ushort_t Bs[128*64];
  const int t = threadIdx.x;
  const int wave = t >> 6, lane = t & 63;
  const int quad = lane >> 4, l16 = lane & 15;
  const int wm = wave >> 1, wn = wave & 1;
  const int lin = blockIdx.x;
  const int xcd = lin & 7, slot = lin >> 3;
  const int d = xcd + 8*(slot/9);
  const int tile = slot - (slot/9)*9;
  const int i0 = (tile/3) * 128, j0 = (tile%3) * 128;
  const size_t dbase = (size_t)d * PL;

  f32x4 acc[4][4];
  const f32x4 z4 = {0.f, 0.f, 0.f, 0.f};
#pragma unroll
  for (int mf = 0; mf < 4; ++mf)
#pragma unroll
    for (int nf = 0; nf < 4; ++nf) acc[mf][nf] = z4;

  for (int kt = 0; kt < 6; ++kt) {
    uint4 va[4], vb[4];
#pragma unroll
    for (int j = 0; j < 4; ++j) {
      int cid = t + j*256;                 // 1024 chunk-slots: 128 rows x 8 chunks
      int row = cid >> 3, c = cid & 7;
      va[j] = *(const uint4*)(a_t + dbase + (size_t)(i0 + row)*N + kt*64 + c*8);
      vb[j] = *(const uint4*)(b_t + dbase + (size_t)(j0 + row)*N + kt*64 + c*8);
    }
    __syncthreads();                       // previous iteration's reads complete
#pragma unroll
    for (int j = 0; j < 4; ++j) {
      int cid = t + j*256;
      int row = cid >> 3, c = cid & 7;
      int p = c ^ (row & 7);               // swizzle: conflict-free frag reads
      *(uint4*)(As + row*64 + p*8) = va[j];
      *(uint4*)(Bs + row*64 + p*8) = vb[j];
    }
    __syncthreads();                       // writes visible to all waves

#pragma unroll
    for (int ks = 0; ks < 2; ++ks) {
      bf16x8 af[4], bfr[4];
#pragma unroll
      for (int f = 0; f < 4; ++f) {
        int ra = wm*64 + f*16 + l16;
        int pa = (ks*4 + quad) ^ (ra & 7);
        af[f] = *(const bf16x8*)(As + ra*64 + pa*8);
        int rb = wn*64 + f*16 + l16;
        int pb = (ks*4 + quad) ^ (rb & 7);
        bfr[f] = *(const bf16x8*)(Bs + rb*64 + pb*8);
      }
#pragma unroll
      for (int mf = 0; mf < 4; ++mf)
#pragma unroll
        for (int nf = 0; nf < 4; ++nf)
          acc[mf][nf] = __builtin_amdgcn_mfma_f32_16x16x32_bf16(af[mf], bfr[nf], acc[mf][nf], 0, 0, 0);
    }
  }
#pragma unroll
  for (int mf = 0; mf < 4; ++mf)
#pragma unroll
    for (int nf = 0; nf < 4; ++nf)
#pragma unroll
      for (int r = 0; r < 4; ++r) {
        int row = wm*64 + mf*16 + quad*4 + r;
        int col = wn*64 + nf*16 + l16;
        s_t[dbase + (size_t)(i0 + row)*N + j0 + col] = f2bf(acc[mf][nf][r]);
      }
}

// ---------------- K3: out = g * (LN(s) @ Wout^T) ------------------------
__global__ __launch_bounds__(256, 3)
void k3(const ushort_t* __restrict__ s_t, const void* __restrict__ gno,
        const void* __restrict__ bno, const ushort_t* __restrict__ wp,
        void* __restrict__ io, const ushort_t* __restrict__ g_t, int gIsWs,
        const int* __restrict__ flag)
{
  __shared__ ushort_t ss[128*136];
  const int t = threadIdx.x;
  const int isf32 = *flag;
  const int wave = t >> 6, lane = t & 63;
  const int quad = lane >> 4, l16 = lane & 15;
  const int R0 = blockIdx.x * 128;
  const ushort_t* Woutp = wp + 5*WSZ;

  // stage s tile [d][R] -> LDS [R][d] via 8x8 register transpose
  {
    const int dg = t >> 4, rg = t & 15;
    const int d0 = dg * 8;
    uint4 v[8];
#pragma unroll
    for (int dd = 0; dd < 8; ++dd)
      v[dd] = *(const uint4*)(s_t + (size_t)(d0 + dd)*PL + R0 + rg*8);
    const ushort_t* sv = (const ushort_t*)v;
#pragma unroll
    for (int rr0 = 0; rr0 < 8; ++rr0) {
      int rr = (rr0 + (t & 7)) & 7;          // lane stagger: kills bank conflicts
      ushort_t w[8];
#pragma unroll
      for (int dd = 0; dd < 8; ++dd) w[dd] = sv[dd*8 + rr];
      *(uint4*)(ss + (rg*8 + rr)*136 + d0) = *(const uint4*)w;
    }
  }
  __syncthreads();

  // layernorm over d (2 threads per row)
  {
    const int r = t >> 1, h = t & 1;
    uint4 q[8];
    float sum = 0.f, sq = 0.f;
#pragma unroll
    for (int j = 0; j < 8; ++j) {
      q[j] = *(const uint4*)(ss + r*136 + (h*8 + j)*8);
      float f[8]; unpack8(q[j], f);
#pragma unroll
      for (int e = 0; e < 8; ++e) { sum += f[e]; sq += f[e]*f[e]; }
    }
    sum += __shfl_xor(sum, 1);
    sq  += __shfl_xor(sq, 1);
    const float mu = sum * 0.0078125f;
    const float rstd = rsqrtf(sq * 0.0078125f - mu*mu + 1e-5f);
#pragma unroll
    for (int j = 0; j < 8; ++j) {
      const int g = h*8 + j;
      float f[8], gm[8], bt[8];
      unpack8(q[j], f);
      load8f(gno, (size_t)g*8, isf32, gm);
      load8f(bno, (size_t)g*8, isf32, bt);
#pragma unroll
      for (int e = 0; e < 8; ++e) f[e] = (f[e] - mu) * rstd * gm[e] + bt[e];
      *(uint4*)(ss + r*136 + g*8) = pack8(f);
    }
  }
  __syncthreads();   // LN writes visible before GEMM fragment reads

  f32x4 acc[2][8];
  const f32x4 z4 = {0.f, 0.f, 0.f, 0.f};
#pragma unroll
  for (int mf = 0; mf < 2; ++mf)
#pragma unroll
    for (int nf = 0; nf < 8; ++nf) acc[mf][nf] = z4;
#pragma unroll
  for (int ks = 0; ks < 4; ++ks) {
    bf16x8 af[2];
#pragma unroll
    for (int mf = 0; mf < 2; ++mf) {
      int row = wave*32 + mf*16 + l16;
      af[mf] = *(const bf16x8*)(ss + row*136 + (ks*4 + quad)*8);
    }
#pragma unroll
    for (int nf = 0; nf < 8; ++nf) {
      size_t foff = (size_t)(((ks*8 + nf)*64 + lane)) * 8;
      bf16x8 b = *(const bf16x8*)(Woutp + foff);
#pragma unroll
      for (int mf = 0; mf < 2; ++mf)
        acc[mf][nf] = __builtin_amdgcn_mfma_f32_16x16x32_bf16(af[mf], b, acc[mf][nf], 0, 0, 0);
    }
  }
  __syncthreads();   // all fragment reads complete before h write-back

#pragma unroll
  for (int mf = 0; mf < 2; ++mf)
#pragma unroll
    for (int nf = 0; nf < 8; ++nf)
#pragma unroll
      for (int r = 0; r < 4; ++r) {
        int row = wave*32 + mf*16 + quad*4 + r;
        int col = nf*16 + l16;
        ss[row*136 + col] = f2bf(acc[mf][nf][r]);
      }
  __syncthreads();

  // gated store: out = g * h, fully vectorized
#pragma unroll
  for (int i = 0; i < 8; ++i) {
    int cid = t + i*256;
    int row = cid >> 4, ch = cid & 15;
    size_t idx = (size_t)(R0 + row)*C + ch*8;
    float gf[8], hf[8], of[8];
    if (gIsWs) unpack8(*(const uint4*)(g_t + idx), gf);
    else       load8f(io, idx, isf32, gf);
    unpack8(*(const uint4*)(ss + row*136 + ch*8), hf);
#pragma unroll
    for (int e = 0; e < 8; ++e) of[e] = gf[e] * hf[e];
    store8(io, idx, isf32, of);
  }
}

extern "C" void kernel_launch(void* const* d_in, const int* in_sizes, int n_in,
                              void* d_out, int out_size, void* d_ws, size_t ws_size,
                              hipStream_t stream) {
  (void)in_sizes; (void)n_in; (void)out_size;
  const void* z    = d_in[0];
  const void* gin  = d_in[1];
  const void* bin  = d_in[2];
  const void* gno  = d_in[3];
  const void* bno  = d_in[4];
  const void* Wa1  = d_in[5];
  const void* Wa2  = d_in[6];
  const void* Wb1  = d_in[7];
  const void* Wb2  = d_in[8];
  const void* Wg   = d_in[9];
  const void* Wout = d_in[10];

  const size_t plane = (size_t)C * PL;                         // padded [d][R] plane
  int* flag     = (int*)d_ws;                                  // 256 B
  ushort_t* wp  = (ushort_t*)((char*)d_ws + 256);              // 6 x 32 KB
  ushort_t* a_t = wp + (size_t)6*WSZ;
  ushort_t* b_t = a_t + plane;
  ushort_t* s_t = b_t + plane;
  ushort_t* g_t = s_t + plane;
  size_t need_g = 256 + (size_t)6*WSZ*2 + (3*plane + (size_t)NR*C)*2;
  int gIsWs = (ws_size >= need_g) ? 1 : 0;

  kdetect<<<1, 256, 0, stream>>>((const unsigned int*)z, flag);
  kprep<<<6, 256, 0, stream>>>(Wa1, Wa2, Wb1, Wb2, Wg, Wout, wp, flag);
  k1<<<NR/64, 256, 0, stream>>>(z, gin, bin, wp, a_t, b_t, d_out, g_t, gIsWs, flag);
  k2<<<1152, 256, 0, stream>>>(a_t, b_t, s_t);
  k3<<<NR/128, 256, 0, stream>>>(s_t, gno, bno, wp, d_out, g_t, gIsWs, flag);
}

// Round 7
// 367.191 us; speedup vs baseline: 1.6676x; 1.1338x over previous
//
#include <hip/hip_runtime.h>
#include <stdint.h>

#define N 384
#define NR (N*N)        // 147456
#define PL (NR + 64)    // padded plane stride
#define C 128
#define WSZ 16384       // 128x128 elements per weight

typedef unsigned short ushort_t;
typedef __attribute__((ext_vector_type(8))) short bf16x8;
typedef __attribute__((ext_vector_type(4))) float f32x4;

__device__ __forceinline__ float bf2f(ushort_t u) {
  union { unsigned int i; float f; } v; v.i = ((unsigned int)u) << 16; return v.f;
}
__device__ __forceinline__ ushort_t f2bf(float f) {
  union { float f; unsigned int i; } v; v.f = f;
  unsigned int u = v.i + 0x7FFF + ((v.i >> 16) & 1);
  return (ushort_t)(u >> 16);
}
__device__ __forceinline__ float sigmoidf_(float x) {
  return 1.0f / (1.0f + __expf(-x));
}
__device__ __forceinline__ void unpack8(uint4 q, float f[8]) {
  const unsigned int* w = (const unsigned int*)&q;
#pragma unroll
  for (int e = 0; e < 4; ++e) {
    f[2*e]   = bf2f((ushort_t)(w[e] & 0xffffu));
    f[2*e+1] = bf2f((ushort_t)(w[e] >> 16));
  }
}
__device__ __forceinline__ uint4 pack8(const float f[8]) {
  uint4 q;
  unsigned int* w = (unsigned int*)&q;
#pragma unroll
  for (int e = 0; e < 4; ++e)
    w[e] = (unsigned int)f2bf(f[2*e]) | ((unsigned int)f2bf(f[2*e+1]) << 16);
  return q;
}

// ---- dtype-dual IO helpers (isf32 is wave-uniform) ---------------------
__device__ __forceinline__ void load8f(const void* p, size_t idx, int isf32, float f[8]) {
  if (isf32) {
    const float* q = (const float*)p + idx;
    const float4 a = ((const float4*)q)[0];
    const float4 b = ((const float4*)q)[1];
    f[0]=a.x; f[1]=a.y; f[2]=a.z; f[3]=a.w;
    f[4]=b.x; f[5]=b.y; f[6]=b.z; f[7]=b.w;
  } else {
    unpack8(*(const uint4*)((const ushort_t*)p + idx), f);
  }
}
__device__ __forceinline__ void store8(void* p, size_t idx, int isf32, const float f[8]) {
  if (isf32) {
    float* q = (float*)p + idx;
    ((float4*)q)[0] = make_float4(f[0], f[1], f[2], f[3]);
    ((float4*)q)[1] = make_float4(f[4], f[5], f[6], f[7]);
  } else {
    *(uint4*)((ushort_t*)p + idx) = pack8(f);
  }
}
__device__ __forceinline__ void store1(void* p, size_t idx, int isf32, float v) {
  if (isf32) ((float*)p)[idx] = v;
  else       ((ushort_t*)p)[idx] = f2bf(v);
}

// ---- dtype detector: fp32 N(0,1) words have exponent in [87,132] -------
__global__ void kdetect(const unsigned int* __restrict__ z, int* __restrict__ flag) {
  const int t = threadIdx.x;
  __shared__ int cnt[4];
  unsigned int u = z[t];
  int e = (u >> 23) & 0xFF;
  int sane = (e >= 87 && e <= 132) ? 1 : 0;
  unsigned long long b = __ballot(sane);
  if ((t & 63) == 0) cnt[t >> 6] = __popcll(b);
  __syncthreads();
  if (t == 0) flag[0] = ((cnt[0] + cnt[1] + cnt[2] + cnt[3]) >= 128) ? 1 : 0;
}

// ---- weight prep: fragment-ordered bf16 copies -------------------------
__global__ void kprep(const void* __restrict__ Wa1, const void* __restrict__ Wa2,
                      const void* __restrict__ Wb1, const void* __restrict__ Wb2,
                      const void* __restrict__ Wg,  const void* __restrict__ Wout,
                      ushort_t* __restrict__ wp, const int* __restrict__ flag)
{
  const int isf32 = *flag;
  const void* src;
  switch (blockIdx.x) {
    case 0: src = Wa1; break;
    case 1: src = Wa2; break;
    case 2: src = Wb1; break;
    case 3: src = Wb2; break;
    case 4: src = Wg;  break;
    default: src = Wout; break;
  }
  ushort_t* dst = wp + (size_t)blockIdx.x * WSZ;
  for (int c = threadIdx.x; c < 2048; c += 256) {
    int ks = c >> 9, nf = (c >> 6) & 7, lane = c & 63;
    int quad = lane >> 4, l16 = lane & 15;
    size_t sidx = (size_t)(nf*16 + l16)*128 + ks*32 + quad*8;
    float f[8]; load8f(src, sidx, isf32, f);
    *(uint4*)(dst + (size_t)c*8) = pack8(f);
  }
}

// ---------------- K1: fused LN(z) + 5 projections (register LN) ---------
// __launch_bounds__(256,2): R5/R6's (256,3) capped VGPR at 84 -> compiler
// spilled to scratch (+168 MB WRITE, +50 MB FETCH vs logical IO). 2 waves/EU
// gives the ~130-reg live set headroom; no spill.
__global__ __launch_bounds__(256, 2)
void k1(const void* __restrict__ z, const void* __restrict__ gin,
        const void* __restrict__ bin, const ushort_t* __restrict__ wp,
        ushort_t* __restrict__ a_t, ushort_t* __restrict__ b_t,
        void* __restrict__ gout, ushort_t* __restrict__ g_t, int gIsWs,
        const int* __restrict__ flag)
{
  __shared__ ushort_t tb[128*72];      // 18 KB: 128 d x 64 rows (+pad to 72)
  const int t = threadIdx.x;
  const int isf32 = *flag;
  const int wave = t >> 6, lane = t & 63;
  const int quad = lane >> 4, l16 = lane & 15;
  const int rg = wave >> 1, ch = wave & 1;
  const int R0 = blockIdx.x * 64;
  const f32x4 z4 = {0.f, 0.f, 0.f, 0.f};

  // ---- A-fragments + in-register layernorm (stats on bf16-rounded z)
  bf16x8 af[2][4];
#pragma unroll
  for (int mf = 0; mf < 2; ++mf) {
    const int row = R0 + rg*32 + mf*16 + l16;
    float x[4][8];
    float s = 0.f, q = 0.f;
#pragma unroll
    for (int ks = 0; ks < 4; ++ks) {
      load8f(z, (size_t)row*C + ks*32 + quad*8, isf32, x[ks]);
#pragma unroll
      for (int e = 0; e < 8; ++e) {
        x[ks][e] = bf2f(f2bf(x[ks][e]));
        s += x[ks][e]; q += x[ks][e]*x[ks][e];
      }
    }
    s += __shfl_xor(s, 16); s += __shfl_xor(s, 32);
    q += __shfl_xor(q, 16); q += __shfl_xor(q, 32);
    const float mu = s * 0.0078125f;
    const float rstd = rsqrtf(q * 0.0078125f - mu*mu + 1e-5f);
#pragma unroll
    for (int ks = 0; ks < 4; ++ks) {
      float ga[8], be[8];
      load8f(gin, (size_t)(ks*32 + quad*8), isf32, ga);
      load8f(bin, (size_t)(ks*32 + quad*8), isf32, be);
      union { alignas(16) ushort_t w[8]; bf16x8 v; } u;
#pragma unroll
      for (int e = 0; e < 8; ++e)
        u.w[e] = f2bf((x[ks][e] - mu) * rstd * ga[e] + be[e]);
      af[mf][ks] = u.v;
    }
  }

  // ---- gated pair projection: dst[d][R] = sig(z@W1^T) * (z@W2^T)
  auto pair = [&](const ushort_t* W1p, const ushort_t* W2p, ushort_t* dst) {
    f32x4 a1[2][4], a2[2][4];
#pragma unroll
    for (int mf = 0; mf < 2; ++mf)
#pragma unroll
      for (int nf = 0; nf < 4; ++nf) { a1[mf][nf] = z4; a2[mf][nf] = z4; }
#pragma unroll
    for (int ks = 0; ks < 4; ++ks)
#pragma unroll
      for (int nf = 0; nf < 4; ++nf) {
        const size_t foff = (size_t)((ks*8 + ch*4 + nf)*64 + lane) * 8;
        bf16x8 b1 = *(const bf16x8*)(W1p + foff);
        bf16x8 b2 = *(const bf16x8*)(W2p + foff);
#pragma unroll
        for (int mf = 0; mf < 2; ++mf) {
          a1[mf][nf] = __builtin_amdgcn_mfma_f32_16x16x32_bf16(af[mf][ks], b1, a1[mf][nf], 0, 0, 0);
          a2[mf][nf] = __builtin_amdgcn_mfma_f32_16x16x32_bf16(af[mf][ks], b2, a2[mf][nf], 0, 0, 0);
        }
      }
#pragma unroll
    for (int mf = 0; mf < 2; ++mf)
#pragma unroll
      for (int nf = 0; nf < 4; ++nf)
#pragma unroll
        for (int r = 0; r < 4; ++r) {
          int rowl = rg*32 + mf*16 + quad*4 + r;       // 0..64
          int col  = ch*64 + nf*16 + l16;              // 0..128 (the d index)
          tb[col*72 + rowl] = f2bf(a2[mf][nf][r] * sigmoidf_(a1[mf][nf][r]));
        }
    __syncthreads();
#pragma unroll
    for (int i = 0; i < 4; ++i) {
      int cid = t + i*256, dl = cid >> 3, rc = cid & 7;  // 128 d x 8 chunks
      uint4 v = *(const uint4*)(tb + dl*72 + rc*8);
      *(uint4*)(dst + (size_t)dl*PL + R0 + rc*8) = v;
    }
    __syncthreads();
  };
  pair(wp + 0*WSZ, wp + 1*WSZ, a_t);
  pair(wp + 2*WSZ, wp + 3*WSZ, b_t);

  // ---- g = sigmoid(z@Wg^T), natural [R][d] layout
  {
    const ushort_t* Wgp = wp + 4*WSZ;
    f32x4 ag[2][4];
#pragma unroll
    for (int mf = 0; mf < 2; ++mf)
#pragma unroll
      for (int nf = 0; nf < 4; ++nf) ag[mf][nf] = z4;
#pragma unroll
    for (int ks = 0; ks < 4; ++ks)
#pragma unroll
      for (int nf = 0; nf < 4; ++nf) {
        const size_t foff = (size_t)((ks*8 + ch*4 + nf)*64 + lane) * 8;
        bf16x8 b = *(const bf16x8*)(Wgp + foff);
#pragma unroll
        for (int mf = 0; mf < 2; ++mf)
          ag[mf][nf] = __builtin_amdgcn_mfma_f32_16x16x32_bf16(af[mf][ks], b, ag[mf][nf], 0, 0, 0);
      }
#pragma unroll
    for (int mf = 0; mf < 2; ++mf)
#pragma unroll
      for (int nf = 0; nf < 4; ++nf)
#pragma unroll
        for (int r = 0; r < 4; ++r) {
          int row = R0 + rg*32 + mf*16 + quad*4 + r;
          int col = ch*64 + nf*16 + l16;
          float v = sigmoidf_(ag[mf][nf][r]);
          size_t idx = (size_t)row*C + col;
          if (gIsWs) g_t[idx] = f2bf(v);
          else       store1(gout, idx, isf32, v);
        }
  }
}

// ---------------- K2: s_d = A_d * B_d^T per channel ---------------------
__global__ __launch_bounds__(256, 2)
void k2(const ushort_t* __restrict__ a_t, const ushort_t* __restrict__ b_t,
        ushort_t* __restrict__ s_t)
{
  __shared__ ushort_t As[128*64];
  __shared__ ushort_t Bs[128*64];
  const int t = threadIdx.x;
  const int wave = t >> 6, lane = t & 63;
  const int quad = lane >> 4, l16 = lane & 15;
  const int wm = wave >> 1, wn = wave & 1;
  const int lin = blockIdx.x;
  const int xcd = lin & 7, slot = lin >> 3;
  const int d = xcd + 8*(slot/9);
  const int tile = slot - (slot/9)*9;
  const int i0 = (tile/3) * 128, j0 = (tile%3) * 128;
  const size_t dbase = (size_t)d * PL;

  f32x4 acc[4][4];
  const f32x4 z4 = {0.f, 0.f, 0.f, 0.f};
#pragma unroll
  for (int mf = 0; mf < 4; ++mf)
#pragma unroll
    for (int nf = 0; nf < 4; ++nf) acc[mf][nf] = z4;

  for (int kt = 0; kt < 6; ++kt) {
    uint4 va[4], vb[4];
#pragma unroll
    for (int j = 0; j < 4; ++j) {
      int cid = t + j*256;                 // 1024 chunk-slots: 128 rows x 8 chunks
      int row = cid >> 3, c = cid & 7;
      va[j] = *(const uint4*)(a_t + dbase + (size_t)(i0 + row)*N + kt*64 + c*8);
      vb[j] = *(const uint4*)(b_t + dbase + (size_t)(j0 + row)*N + kt*64 + c*8);
    }
    __syncthreads();                       // previous iteration's reads complete
#pragma unroll
    for (int j = 0; j < 4; ++j) {
      int cid = t + j*256;
      int row = cid >> 3, c = cid & 7;
      int p = c ^ (row & 7);               // swizzle: conflict-free frag reads
      *(uint4*)(As + row*64 + p*8) = va[j];
      *(uint4*)(Bs + row*64 + p*8) = vb[j];
    }
    __syncthreads();                       // writes visible to all waves

#pragma unroll
    for (int ks = 0; ks < 2; ++ks) {
      bf16x8 af[4], bfr[4];
#pragma unroll
      for (int f = 0; f < 4; ++f) {
        int ra = wm*64 + f*16 + l16;
        int pa = (ks*4 + quad) ^ (ra & 7);
        af[f] = *(const bf16x8*)(As + ra*64 + pa*8);
        int rb = wn*64 + f*16 + l16;
        int pb = (ks*4 + quad) ^ (rb & 7);
        bfr[f] = *(const bf16x8*)(Bs + rb*64 + pb*8);
      }
#pragma unroll
      for (int mf = 0; mf < 4; ++mf)
#pragma unroll
        for (int nf = 0; nf < 4; ++nf)
          acc[mf][nf] = __builtin_amdgcn_mfma_f32_16x16x32_bf16(af[mf], bfr[nf], acc[mf][nf], 0, 0, 0);
    }
  }
#pragma unroll
  for (int mf = 0; mf < 4; ++mf)
#pragma unroll
    for (int nf = 0; nf < 4; ++nf)
#pragma unroll
      for (int r = 0; r < 4; ++r) {
        int row = wm*64 + mf*16 + quad*4 + r;
        int col = wn*64 + nf*16 + l16;
        s_t[dbase + (size_t)(i0 + row)*N + j0 + col] = f2bf(acc[mf][nf][r]);
      }
}

// ---------------- K3: out = g * (LN(s) @ Wout^T) ------------------------
__global__ __launch_bounds__(256, 3)
void k3(const ushort_t* __restrict__ s_t, const void* __restrict__ gno,
        const void* __restrict__ bno, const ushort_t* __restrict__ wp,
        void* __restrict__ io, const ushort_t* __restrict__ g_t, int gIsWs,
        const int* __restrict__ flag)
{
  __shared__ ushort_t ss[128*136];
  const int t = threadIdx.x;
  const int isf32 = *flag;
  const int wave = t >> 6, lane = t & 63;
  const int quad = lane >> 4, l16 = lane & 15;
  const int R0 = blockIdx.x * 128;
  const ushort_t* Woutp = wp + 5*WSZ;

  // stage s tile [d][R] -> LDS [R][d] via 8x8 register transpose
  {
    const int dg = t >> 4, rg = t & 15;
    const int d0 = dg * 8;
    uint4 v[8];
#pragma unroll
    for (int dd = 0; dd < 8; ++dd)
      v[dd] = *(const uint4*)(s_t + (size_t)(d0 + dd)*PL + R0 + rg*8);
    const ushort_t* sv = (const ushort_t*)v;
#pragma unroll
    for (int rr0 = 0; rr0 < 8; ++rr0) {
      int rr = (rr0 + (t & 7)) & 7;          // lane stagger: kills bank conflicts
      ushort_t w[8];
#pragma unroll
      for (int dd = 0; dd < 8; ++dd) w[dd] = sv[dd*8 + rr];
      *(uint4*)(ss + (rg*8 + rr)*136 + d0) = *(const uint4*)w;
    }
  }
  __syncthreads();

  // layernorm over d (2 threads per row)
  {
    const int r = t >> 1, h = t & 1;
    uint4 q[8];
    float sum = 0.f, sq = 0.f;
#pragma unroll
    for (int j = 0; j < 8; ++j) {
      q[j] = *(const uint4*)(ss + r*136 + (h*8 + j)*8);
      float f[8]; unpack8(q[j], f);
#pragma unroll
      for (int e = 0; e < 8; ++e) { sum += f[e]; sq += f[e]*f[e]; }
    }
    sum += __shfl_xor(sum, 1);
    sq  += __shfl_xor(sq, 1);
    const float mu = sum * 0.0078125f;
    const float rstd = rsqrtf(sq * 0.0078125f - mu*mu + 1e-5f);
#pragma unroll
    for (int j = 0; j < 8; ++j) {
      const int g = h*8 + j;
      float f[8], gm[8], bt[8];
      unpack8(q[j], f);
      load8f(gno, (size_t)g*8, isf32, gm);
      load8f(bno, (size_t)g*8, isf32, bt);
#pragma unroll
      for (int e = 0; e < 8; ++e) f[e] = (f[e] - mu) * rstd * gm[e] + bt[e];
      *(uint4*)(ss + r*136 + g*8) = pack8(f);
    }
  }
  __syncthreads();   // LN writes visible before GEMM fragment reads

  f32x4 acc[2][8];
  const f32x4 z4 = {0.f, 0.f, 0.f, 0.f};
#pragma unroll
  for (int mf = 0; mf < 2; ++mf)
#pragma unroll
    for (int nf = 0; nf < 8; ++nf) acc[mf][nf] = z4;
#pragma unroll
  for (int ks = 0; ks < 4; ++ks) {
    bf16x8 af[2];
#pragma unroll
    for (int mf = 0; mf < 2; ++mf) {
      int row = wave*32 + mf*16 + l16;
      af[mf] = *(const bf16x8*)(ss + row*136 + (ks*4 + quad)*8);
    }
#pragma unroll
    for (int nf = 0; nf < 8; ++nf) {
      size_t foff = (size_t)(((ks*8 + nf)*64 + lane)) * 8;
      bf16x8 b = *(const bf16x8*)(Woutp + foff);
#pragma unroll
      for (int mf = 0; mf < 2; ++mf)
        acc[mf][nf] = __builtin_amdgcn_mfma_f32_16x16x32_bf16(af[mf], b, acc[mf][nf], 0, 0, 0);
    }
  }
  __syncthreads();   // all fragment reads complete before h write-back

#pragma unroll
  for (int mf = 0; mf < 2; ++mf)
#pragma unroll
    for (int nf = 0; nf < 8; ++nf)
#pragma unroll
      for (int r = 0; r < 4; ++r) {
        int row = wave*32 + mf*16 + quad*4 + r;
        int col = nf*16 + l16;
        ss[row*136 + col] = f2bf(acc[mf][nf][r]);
      }
  __syncthreads();

  // gated store: out = g * h, fully vectorized
#pragma unroll
  for (int i = 0; i < 8; ++i) {
    int cid = t + i*256;
    int row = cid >> 4, ch = cid & 15;
    size_t idx = (size_t)(R0 + row)*C + ch*8;
    float gf[8], hf[8], of[8];
    if (gIsWs) unpack8(*(const uint4*)(g_t + idx), gf);
    else       load8f(io, idx, isf32, gf);
    unpack8(*(const uint4*)(ss + row*136 + ch*8), hf);
#pragma unroll
    for (int e = 0; e < 8; ++e) of[e] = gf[e] * hf[e];
    store8(io, idx, isf32, of);
  }
}

extern "C" void kernel_launch(void* const* d_in, const int* in_sizes, int n_in,
                              void* d_out, int out_size, void* d_ws, size_t ws_size,
                              hipStream_t stream) {
  (void)in_sizes; (void)n_in; (void)out_size;
  const void* z    = d_in[0];
  const void* gin  = d_in[1];
  const void* bin  = d_in[2];
  const void* gno  = d_in[3];
  const void* bno  = d_in[4];
  const void* Wa1  = d_in[5];
  const void* Wa2  = d_in[6];
  const void* Wb1  = d_in[7];
  const void* Wb2  = d_in[8];
  const void* Wg   = d_in[9];
  const void* Wout = d_in[10];

  const size_t plane = (size_t)C * PL;                         // padded [d][R] plane
  int* flag     = (int*)d_ws;                                  // 256 B
  ushort_t* wp  = (ushort_t*)((char*)d_ws + 256);              // 6 x 32 KB
  ushort_t* a_t = wp + (size_t)6*WSZ;
  ushort_t* b_t = a_t + plane;
  ushort_t* s_t = b_t + plane;
  ushort_t* g_t = s_t + plane;
  size_t need_g = 256 + (size_t)6*WSZ*2 + (3*plane + (size_t)NR*C)*2;
  int gIsWs = (ws_size >= need_g) ? 1 : 0;

  kdetect<<<1, 256, 0, stream>>>((const unsigned int*)z, flag);
  kprep<<<6, 256, 0, stream>>>(Wa1, Wa2, Wb1, Wb2, Wg, Wout, wp, flag);
  k1<<<NR/64, 256, 0, stream>>>(z, gin, bin, wp, a_t, b_t, d_out, g_t, gIsWs, flag);
  k2<<<1152, 256, 0, stream>>>(a_t, b_t, s_t);
  k3<<<NR/128, 256, 0, stream>>>(s_t, gno, bno, wp, d_out, g_t, gIsWs, flag);
}

// Round 8
// 366.377 us; speedup vs baseline: 1.6713x; 1.0022x over previous
//
#include <hip/hip_runtime.h>
#include <stdint.h>

#define N 384
#define NR (N*N)        // 147456
#define PL (NR + 64)    // padded plane stride
#define C 128
#define WSZ 16384       // 128x128 elements per weight

typedef unsigned short ushort_t;
typedef __attribute__((ext_vector_type(8))) short bf16x8;
typedef __attribute__((ext_vector_type(4))) float f32x4;

__device__ __forceinline__ float bf2f(ushort_t u) {
  union { unsigned int i; float f; } v; v.i = ((unsigned int)u) << 16; return v.f;
}
__device__ __forceinline__ ushort_t f2bf(float f) {
  union { float f; unsigned int i; } v; v.f = f;
  unsigned int u = v.i + 0x7FFF + ((v.i >> 16) & 1);
  return (ushort_t)(u >> 16);
}
__device__ __forceinline__ float sigmoidf_(float x) {
  return 1.0f / (1.0f + __expf(-x));
}
__device__ __forceinline__ void unpack8(uint4 q, float f[8]) {
  const unsigned int* w = (const unsigned int*)&q;
#pragma unroll
  for (int e = 0; e < 4; ++e) {
    f[2*e]   = bf2f((ushort_t)(w[e] & 0xffffu));
    f[2*e+1] = bf2f((ushort_t)(w[e] >> 16));
  }
}
__device__ __forceinline__ uint4 pack8(const float f[8]) {
  uint4 q;
  unsigned int* w = (unsigned int*)&q;
#pragma unroll
  for (int e = 0; e < 4; ++e)
    w[e] = (unsigned int)f2bf(f[2*e]) | ((unsigned int)f2bf(f[2*e+1]) << 16);
  return q;
}

// ---- dtype-dual IO helpers (isf32 is wave-uniform) ---------------------
__device__ __forceinline__ void load8f(const void* p, size_t idx, int isf32, float f[8]) {
  if (isf32) {
    const float* q = (const float*)p + idx;
    const float4 a = ((const float4*)q)[0];
    const float4 b = ((const float4*)q)[1];
    f[0]=a.x; f[1]=a.y; f[2]=a.z; f[3]=a.w;
    f[4]=b.x; f[5]=b.y; f[6]=b.z; f[7]=b.w;
  } else {
    unpack8(*(const uint4*)((const ushort_t*)p + idx), f);
  }
}
__device__ __forceinline__ void store8(void* p, size_t idx, int isf32, const float f[8]) {
  if (isf32) {
    float* q = (float*)p + idx;
    ((float4*)q)[0] = make_float4(f[0], f[1], f[2], f[3]);
    ((float4*)q)[1] = make_float4(f[4], f[5], f[6], f[7]);
  } else {
    *(uint4*)((ushort_t*)p + idx) = pack8(f);
  }
}
__device__ __forceinline__ void store1(void* p, size_t idx, int isf32, float v) {
  if (isf32) ((float*)p)[idx] = v;
  else       ((ushort_t*)p)[idx] = f2bf(v);
}

// ---- weight prep + inline dtype detection ------------------------------
// Each block independently detects dtype from z's first 256 words (fp32
// N(0,1) words have exponent in [87,132]; bf16-pair reinterpretation fails
// this for ~half the words). Block 0 publishes the flag for k1/k3.
__global__ void kprep(const unsigned int* __restrict__ zw,
                      const void* __restrict__ Wa1, const void* __restrict__ Wa2,
                      const void* __restrict__ Wb1, const void* __restrict__ Wb2,
                      const void* __restrict__ Wg,  const void* __restrict__ Wout,
                      ushort_t* __restrict__ wp, int* __restrict__ flag)
{
  const int t = threadIdx.x;
  __shared__ int cnt[4];
  {
    unsigned int u = zw[t];
    int e = (u >> 23) & 0xFF;
    int sane = (e >= 87 && e <= 132) ? 1 : 0;
    unsigned long long b = __ballot(sane);
    if ((t & 63) == 0) cnt[t >> 6] = __popcll(b);
  }
  __syncthreads();
  const int isf32 = ((cnt[0] + cnt[1] + cnt[2] + cnt[3]) >= 128) ? 1 : 0;
  if (blockIdx.x == 0 && t == 0) flag[0] = isf32;

  const void* src;
  switch (blockIdx.x) {
    case 0: src = Wa1; break;
    case 1: src = Wa2; break;
    case 2: src = Wb1; break;
    case 3: src = Wb2; break;
    case 4: src = Wg;  break;
    default: src = Wout; break;
  }
  ushort_t* dst = wp + (size_t)blockIdx.x * WSZ;
  for (int c = t; c < 2048; c += 256) {
    int ks = c >> 9, nf = (c >> 6) & 7, lane = c & 63;
    int quad = lane >> 4, l16 = lane & 15;
    size_t sidx = (size_t)(nf*16 + l16)*128 + ks*32 + quad*8;
    float f[8]; load8f(src, sidx, isf32, f);
    *(uint4*)(dst + (size_t)c*8) = pack8(f);
  }
}

// ---------------- K1: fused LN(z) + 5 projections (register LN) ---------
// (256,2): (256,3) caps arch VGPR at ~84 -> spill (R5/R6 evidence).
__global__ __launch_bounds__(256, 2)
void k1(const void* __restrict__ z, const void* __restrict__ gin,
        const void* __restrict__ bin, const ushort_t* __restrict__ wp,
        ushort_t* __restrict__ a_t, ushort_t* __restrict__ b_t,
        void* __restrict__ gout, ushort_t* __restrict__ g_t, int gIsWs,
        const int* __restrict__ flag)
{
  __shared__ ushort_t tb[128*72];      // 18 KB: 128 d x 64 rows (+pad to 72)
  const int t = threadIdx.x;
  const int isf32 = *flag;
  const int wave = t >> 6, lane = t & 63;
  const int quad = lane >> 4, l16 = lane & 15;
  const int rg = wave >> 1, ch = wave & 1;
  const int R0 = blockIdx.x * 64;
  const f32x4 z4 = {0.f, 0.f, 0.f, 0.f};

  // ---- A-fragments + in-register layernorm (stats on bf16-rounded z)
  bf16x8 af[2][4];
#pragma unroll
  for (int mf = 0; mf < 2; ++mf) {
    const int row = R0 + rg*32 + mf*16 + l16;
    float x[4][8];
    float s = 0.f, q = 0.f;
#pragma unroll
    for (int ks = 0; ks < 4; ++ks) {
      load8f(z, (size_t)row*C + ks*32 + quad*8, isf32, x[ks]);
#pragma unroll
      for (int e = 0; e < 8; ++e) {
        x[ks][e] = bf2f(f2bf(x[ks][e]));
        s += x[ks][e]; q += x[ks][e]*x[ks][e];
      }
    }
    s += __shfl_xor(s, 16); s += __shfl_xor(s, 32);
    q += __shfl_xor(q, 16); q += __shfl_xor(q, 32);
    const float mu = s * 0.0078125f;
    const float rstd = rsqrtf(q * 0.0078125f - mu*mu + 1e-5f);
#pragma unroll
    for (int ks = 0; ks < 4; ++ks) {
      float ga[8], be[8];
      load8f(gin, (size_t)(ks*32 + quad*8), isf32, ga);
      load8f(bin, (size_t)(ks*32 + quad*8), isf32, be);
      union { alignas(16) ushort_t w[8]; bf16x8 v; } u;
#pragma unroll
      for (int e = 0; e < 8; ++e)
        u.w[e] = f2bf((x[ks][e] - mu) * rstd * ga[e] + be[e]);
      af[mf][ks] = u.v;
    }
  }

  // ---- gated pair projection: dst[d][R] = sig(z@W1^T) * (z@W2^T)
  auto pair = [&](const ushort_t* W1p, const ushort_t* W2p, ushort_t* dst) {
    f32x4 a1[2][4], a2[2][4];
#pragma unroll
    for (int mf = 0; mf < 2; ++mf)
#pragma unroll
      for (int nf = 0; nf < 4; ++nf) { a1[mf][nf] = z4; a2[mf][nf] = z4; }
#pragma unroll
    for (int ks = 0; ks < 4; ++ks)
#pragma unroll
      for (int nf = 0; nf < 4; ++nf) {
        const size_t foff = (size_t)((ks*8 + ch*4 + nf)*64 + lane) * 8;
        bf16x8 b1 = *(const bf16x8*)(W1p + foff);
        bf16x8 b2 = *(const bf16x8*)(W2p + foff);
#pragma unroll
        for (int mf = 0; mf < 2; ++mf) {
          a1[mf][nf] = __builtin_amdgcn_mfma_f32_16x16x32_bf16(af[mf][ks], b1, a1[mf][nf], 0, 0, 0);
          a2[mf][nf] = __builtin_amdgcn_mfma_f32_16x16x32_bf16(af[mf][ks], b2, a2[mf][nf], 0, 0, 0);
        }
      }
#pragma unroll
    for (int mf = 0; mf < 2; ++mf)
#pragma unroll
      for (int nf = 0; nf < 4; ++nf)
#pragma unroll
        for (int r = 0; r < 4; ++r) {
          int rowl = rg*32 + mf*16 + quad*4 + r;       // 0..64
          int col  = ch*64 + nf*16 + l16;              // 0..128 (the d index)
          tb[col*72 + rowl] = f2bf(a2[mf][nf][r] * sigmoidf_(a1[mf][nf][r]));
        }
    __syncthreads();
#pragma unroll
    for (int i = 0; i < 4; ++i) {
      int cid = t + i*256, dl = cid >> 3, rc = cid & 7;  // 128 d x 8 chunks
      uint4 v = *(const uint4*)(tb + dl*72 + rc*8);
      *(uint4*)(dst + (size_t)dl*PL + R0 + rc*8) = v;
    }
    __syncthreads();
  };
  pair(wp + 0*WSZ, wp + 1*WSZ, a_t);
  pair(wp + 2*WSZ, wp + 3*WSZ, b_t);

  // ---- g = sigmoid(z@Wg^T), natural [R][d] layout
  {
    const ushort_t* Wgp = wp + 4*WSZ;
    f32x4 ag[2][4];
#pragma unroll
    for (int mf = 0; mf < 2; ++mf)
#pragma unroll
      for (int nf = 0; nf < 4; ++nf) ag[mf][nf] = z4;
#pragma unroll
    for (int ks = 0; ks < 4; ++ks)
#pragma unroll
      for (int nf = 0; nf < 4; ++nf) {
        const size_t foff = (size_t)((ks*8 + ch*4 + nf)*64 + lane) * 8;
        bf16x8 b = *(const bf16x8*)(Wgp + foff);
#pragma unroll
        for (int mf = 0; mf < 2; ++mf)
          ag[mf][nf] = __builtin_amdgcn_mfma_f32_16x16x32_bf16(af[mf][ks], b, ag[mf][nf], 0, 0, 0);
      }
#pragma unroll
    for (int mf = 0; mf < 2; ++mf)
#pragma unroll
      for (int nf = 0; nf < 4; ++nf)
#pragma unroll
        for (int r = 0; r < 4; ++r) {
          int row = R0 + rg*32 + mf*16 + quad*4 + r;
          int col = ch*64 + nf*16 + l16;
          float v = sigmoidf_(ag[mf][nf][r]);
          size_t idx = (size_t)row*C + col;
          if (gIsWs) g_t[idx] = f2bf(v);
          else       store1(gout, idx, isf32, v);
        }
  }
}

// ---------------- K2: s_d = A_d * B_d^T per channel ---------------------
// (256,3): ~64 arch VGPR + 64 acc = 128 unified <= 170 cap -> no spill,
// 12 waves/CU instead of 8.
__global__ __launch_bounds__(256, 3)
void k2(const ushort_t* __restrict__ a_t, const ushort_t* __restrict__ b_t,
        ushort_t* __restrict__ s_t)
{
  __shared__ ushort_t As[128*64];
  __shared__ ushort_t Bs[128*64];
  const int t = threadIdx.x;
  const int wave = t >> 6, lane = t & 63;
  const int quad = lane >> 4, l16 = lane & 15;
  const int wm = wave >> 1, wn = wave & 1;
  const int lin = blockIdx.x;
  const int xcd = lin & 7, slot = lin >> 3;
  const int d = xcd + 8*(slot/9);
  const int tile = slot - (slot/9)*9;
  const int i0 = (tile/3) * 128, j0 = (tile%3) * 128;
  const size_t dbase = (size_t)d * PL;

  f32x4 acc[4][4];
  const f32x4 z4 = {0.f, 0.f, 0.f, 0.f};
#pragma unroll
  for (int mf = 0; mf < 4; ++mf)
#pragma unroll
    for (int nf = 0; nf < 4; ++nf) acc[mf][nf] = z4;

  for (int kt = 0; kt < 6; ++kt) {
    uint4 va[4], vb[4];
#pragma unroll
    for (int j = 0; j < 4; ++j) {
      int cid = t + j*256;                 // 1024 chunk-slots: 128 rows x 8 chunks
      int row = cid >> 3, c = cid & 7;
      va[j] = *(const uint4*)(a_t + dbase + (size_t)(i0 + row)*N + kt*64 + c*8);
      vb[j] = *(const uint4*)(b_t + dbase + (size_t)(j0 + row)*N + kt*64 + c*8);
    }
    __syncthreads();                       // previous iteration's reads complete
#pragma unroll
    for (int j = 0; j < 4; ++j) {
      int cid = t + j*256;
      int row = cid >> 3, c = cid & 7;
      int p = c ^ (row & 7);               // swizzle: conflict-free frag reads
      *(uint4*)(As + row*64 + p*8) = va[j];
      *(uint4*)(Bs + row*64 + p*8) = vb[j];
    }
    __syncthreads();                       // writes visible to all waves

#pragma unroll
    for (int ks = 0; ks < 2; ++ks) {
      bf16x8 af[4], bfr[4];
#pragma unroll
      for (int f = 0; f < 4; ++f) {
        int ra = wm*64 + f*16 + l16;
        int pa = (ks*4 + quad) ^ (ra & 7);
        af[f] = *(const bf16x8*)(As + ra*64 + pa*8);
        int rb = wn*64 + f*16 + l16;
        int pb = (ks*4 + quad) ^ (rb & 7);
        bfr[f] = *(const bf16x8*)(Bs + rb*64 + pb*8);
      }
#pragma unroll
      for (int mf = 0; mf < 4; ++mf)
#pragma unroll
        for (int nf = 0; nf < 4; ++nf)
          acc[mf][nf] = __builtin_amdgcn_mfma_f32_16x16x32_bf16(af[mf], bfr[nf], acc[mf][nf], 0, 0, 0);
    }
  }
#pragma unroll
  for (int mf = 0; mf < 4; ++mf)
#pragma unroll
    for (int nf = 0; nf < 4; ++nf)
#pragma unroll
      for (int r = 0; r < 4; ++r) {
        int row = wm*64 + mf*16 + quad*4 + r;
        int col = wn*64 + nf*16 + l16;
        s_t[dbase + (size_t)(i0 + row)*N + j0 + col] = f2bf(acc[mf][nf][r]);
      }
}

// ---------------- K3: out = g * (LN(s) @ Wout^T) ------------------------
// (256,2): same de-spill rationale as k1 (acc[2][8]=64 + staging 32 + LN 32
// exceeds the (256,3) ~85 arch split).
__global__ __launch_bounds__(256, 2)
void k3(const ushort_t* __restrict__ s_t, const void* __restrict__ gno,
        const void* __restrict__ bno, const ushort_t* __restrict__ wp,
        void* __restrict__ io, const ushort_t* __restrict__ g_t, int gIsWs,
        const int* __restrict__ flag)
{
  __shared__ ushort_t ss[128*136];
  const int t = threadIdx.x;
  const int isf32 = *flag;
  const int wave = t >> 6, lane = t & 63;
  const int quad = lane >> 4, l16 = lane & 15;
  const int R0 = blockIdx.x * 128;
  const ushort_t* Woutp = wp + 5*WSZ;

  // stage s tile [d][R] -> LDS [R][d] via 8x8 register transpose
  {
    const int dg = t >> 4, rg = t & 15;
    const int d0 = dg * 8;
    uint4 v[8];
#pragma unroll
    for (int dd = 0; dd < 8; ++dd)
      v[dd] = *(const uint4*)(s_t + (size_t)(d0 + dd)*PL + R0 + rg*8);
    const ushort_t* sv = (const ushort_t*)v;
#pragma unroll
    for (int rr0 = 0; rr0 < 8; ++rr0) {
      int rr = (rr0 + (t & 7)) & 7;          // lane stagger: kills bank conflicts
      ushort_t w[8];
#pragma unroll
      for (int dd = 0; dd < 8; ++dd) w[dd] = sv[dd*8 + rr];
      *(uint4*)(ss + (rg*8 + rr)*136 + d0) = *(const uint4*)w;
    }
  }
  __syncthreads();

  // layernorm over d (2 threads per row)
  {
    const int r = t >> 1, h = t & 1;
    uint4 q[8];
    float sum = 0.f, sq = 0.f;
#pragma unroll
    for (int j = 0; j < 8; ++j) {
      q[j] = *(const uint4*)(ss + r*136 + (h*8 + j)*8);
      float f[8]; unpack8(q[j], f);
#pragma unroll
      for (int e = 0; e < 8; ++e) { sum += f[e]; sq += f[e]*f[e]; }
    }
    sum += __shfl_xor(sum, 1);
    sq  += __shfl_xor(sq, 1);
    const float mu = sum * 0.0078125f;
    const float rstd = rsqrtf(sq * 0.0078125f - mu*mu + 1e-5f);
#pragma unroll
    for (int j = 0; j < 8; ++j) {
      const int g = h*8 + j;
      float f[8], gm[8], bt[8];
      unpack8(q[j], f);
      load8f(gno, (size_t)g*8, isf32, gm);
      load8f(bno, (size_t)g*8, isf32, bt);
#pragma unroll
      for (int e = 0; e < 8; ++e) f[e] = (f[e] - mu) * rstd * gm[e] + bt[e];
      *(uint4*)(ss + r*136 + g*8) = pack8(f);
    }
  }
  __syncthreads();   // LN writes visible before GEMM fragment reads

  f32x4 acc[2][8];
  const f32x4 z4 = {0.f, 0.f, 0.f, 0.f};
#pragma unroll
  for (int mf = 0; mf < 2; ++mf)
#pragma unroll
    for (int nf = 0; nf < 8; ++nf) acc[mf][nf] = z4;
#pragma unroll
  for (int ks = 0; ks < 4; ++ks) {
    bf16x8 af[2];
#pragma unroll
    for (int mf = 0; mf < 2; ++mf) {
      int row = wave*32 + mf*16 + l16;
      af[mf] = *(const bf16x8*)(ss + row*136 + (ks*4 + quad)*8);
    }
#pragma unroll
    for (int nf = 0; nf < 8; ++nf) {
      size_t foff = (size_t)(((ks*8 + nf)*64 + lane)) * 8;
      bf16x8 b = *(const bf16x8*)(Woutp + foff);
#pragma unroll
      for (int mf = 0; mf < 2; ++mf)
        acc[mf][nf] = __builtin_amdgcn_mfma_f32_16x16x32_bf16(af[mf], b, acc[mf][nf], 0, 0, 0);
    }
  }
  __syncthreads();   // all fragment reads complete before h write-back

#pragma unroll
  for (int mf = 0; mf < 2; ++mf)
#pragma unroll
    for (int nf = 0; nf < 8; ++nf)
#pragma unroll
      for (int r = 0; r < 4; ++r) {
        int row = wave*32 + mf*16 + quad*4 + r;
        int col = nf*16 + l16;
        ss[row*136 + col] = f2bf(acc[mf][nf][r]);
      }
  __syncthreads();

  // gated store: out = g * h, fully vectorized
#pragma unroll
  for (int i = 0; i < 8; ++i) {
    int cid = t + i*256;
    int row = cid >> 4, ch = cid & 15;
    size_t idx = (size_t)(R0 + row)*C + ch*8;
    float gf[8], hf[8], of[8];
    if (gIsWs) unpack8(*(const uint4*)(g_t + idx), gf);
    else       load8f(io, idx, isf32, gf);
    unpack8(*(const uint4*)(ss + row*136 + ch*8), hf);
#pragma unroll
    for (int e = 0; e < 8; ++e) of[e] = gf[e] * hf[e];
    store8(io, idx, isf32, of);
  }
}

extern "C" void kernel_launch(void* const* d_in, const int* in_sizes, int n_in,
                              void* d_out, int out_size, void* d_ws, size_t ws_size,
                              hipStream_t stream) {
  (void)in_sizes; (void)n_in; (void)out_size;
  const void* z    = d_in[0];
  const void* gin  = d_in[1];
  const void* bin  = d_in[2];
  const void* gno  = d_in[3];
  const void* bno  = d_in[4];
  const void* Wa1  = d_in[5];
  const void* Wa2  = d_in[6];
  const void* Wb1  = d_in[7];
  const void* Wb2  = d_in[8];
  const void* Wg   = d_in[9];
  const void* Wout = d_in[10];

  const size_t plane = (size_t)C * PL;                         // padded [d][R] plane
  int* flag     = (int*)d_ws;                                  // 256 B
  ushort_t* wp  = (ushort_t*)((char*)d_ws + 256);              // 6 x 32 KB
  ushort_t* a_t = wp + (size_t)6*WSZ;
  ushort_t* b_t = a_t + plane;
  ushort_t* s_t = b_t + plane;
  ushort_t* g_t = s_t + plane;
  size_t need_g = 256 + (size_t)6*WSZ*2 + (3*plane + (size_t)NR*C)*2;
  int gIsWs = (ws_size >= need_g) ? 1 : 0;

  kprep<<<6, 256, 0, stream>>>((const unsigned int*)z, Wa1, Wa2, Wb1, Wb2, Wg, Wout, wp, flag);
  k1<<<NR/64, 256, 0, stream>>>(z, gin, bin, wp, a_t, b_t, d_out, g_t, gIsWs, flag);
  k2<<<1152, 256, 0, stream>>>(a_t, b_t, s_t);
  k3<<<NR/128, 256, 0, stream>>>(s_t, gno, bno, wp, d_out, g_t, gIsWs, flag);
}